// Round 1
// baseline (662.462 us; speedup 1.0000x reference)
//
#include <hip/hip_runtime.h>

// GNB dispersion-energy graph kernel.
// Inputs (setup_inputs order):
//   d_in[0]: Z          int32  [n_nodes]        n_nodes = in_sizes[0]
//   d_in[1]: edge_index int32  [2, n_edges]     n_edges = in_sizes[1]/2
//   d_in[2]: lengths    fp32   [n_edges]
// Output: node_energy fp32 [n_nodes]
//
// ws layout: [cn: int32 x n_nodes][sC6: f32 x n_nodes][qR: f32 x n_nodes]

// GNB_TABLE columns 2 (R) and 3 (C6) only; rows 58..71 are zero.
__device__ __constant__ float2 GNB_RC6[87] = {
    {0.f, 0.f},
    {3.6516f, 95.99f},   {2.1843f, 40.67f},   {1.2711f, 70.21f},
    {3.3497f, 114.51f},  {2.7079f, 152.36f},  {1.8219f, 184.28f},
    {2.4667f, 482.54f},  {2.365f, 405.57f},   {1.5062f, 218.45f},
    {1.8233f, 174.81f},  {1.3974f, 181.7f},   {3.3515f, 263.02f},
    {3.0102f, 228.1f},   {3.1629f, 359.43f},  {3.2554f, 3222.12f},
    {2.9539f, 2144.49f}, {3.0368f, 2072.46f}, {2.6598f, 1357.42f},
    {4.0877f, 1406.65f}, {4.1275f, 1058.36f}, {9.7282f, 11498.73f},
    {8.5322f, 3361.33f}, {7.2344f, 2095.91f}, {5.3605f, 1049.31f},
    {3.718f, 966.27f},   {3.6408f, 1571.36f}, {3.4961f, 1183.59f},
    {3.5108f, 787.76f},  {3.0537f, 563.93f},  {3.0261f, 592.91f},
    {3.1735f, 430.82f},  {3.1773f, 812.57f},  {3.8357f, 4533.53f},
    {3.1109f, 3440.92f}, {3.2122f, 3859.82f}, {2.8263f, 2729.6f},
    {2.412f, 1864.19f},  {1.894f, 1175.73f},  {11.2061f, 32141.18f},
    {6.821f, 27655.14f}, {7.2367f, 2864.2f},  {3.901f, 3563.45f},
    {4.0857f, 3266.43f}, {4.045f, 3967.23f},  {3.4813f, 2233.82f},
    {3.0487f, 1393.49f}, {2.7795f, 1315.09f}, {2.8673f, 1311.47f},
    {3.3339f, 1460.56f}, {3.0086f, 1662.99f}, {3.9919f, 8089.97f},
    {3.4209f, 6887.05f}, {3.5649f, 8799.32f}, {3.0288f, 6136.5f},
    {2.262f, 3757.31f},  {1.3837f, 2561.18f}, {12.171f, 66580.83f},
    {0.f,0.f},{0.f,0.f},{0.f,0.f},{0.f,0.f},{0.f,0.f},{0.f,0.f},{0.f,0.f},
    {0.f,0.f},{0.f,0.f},{0.f,0.f},{0.f,0.f},{0.f,0.f},{0.f,0.f},{0.f,0.f},
    {6.0791f, 27593.76f}, {5.7661f, 15364.65f}, {3.6366f, 2734.5f},
    {4.241f, 4801.82f},   {4.1348f, 5685.94f},  {3.4213f, 2786.0f},
    {3.2486f, 2699.79f},  {2.9588f, 2282.6f},   {2.9381f, 2476.79f},
    {2.7711f, 2988.7f},   {2.5816f, 2506.63f},  {3.785f, 8916.84f},
    {3.5381f, 8694.22f},  {3.6985f, 11821.61f}, {3.0551f, 8410.64f},
};

__global__ void gnb_init(float* __restrict__ out, int* __restrict__ cn, int n_nodes) {
    int i = blockIdx.x * blockDim.x + threadIdx.x;
    if (i < n_nodes) { out[i] = 0.0f; cn[i] = 0; }
}

__global__ void gnb_degree(const int* __restrict__ recv, int* __restrict__ cn, int n_edges) {
    int i = blockIdx.x * blockDim.x + threadIdx.x;
    int base = i * 4;
    if (base + 3 < n_edges) {
        int4 r = *(const int4*)(recv + base);
        atomicAdd(&cn[r.x], 1);
        atomicAdd(&cn[r.y], 1);
        atomicAdd(&cn[r.z], 1);
        atomicAdd(&cn[r.w], 1);
    } else {
        for (int e = base; e < n_edges; ++e) atomicAdd(&cn[recv[e]], 1);
    }
}

// sC6 = sqrt(C6_i), qR = R_i^(1/4): edge pass then needs zero sqrts.
__global__ void gnb_params(const int* __restrict__ Z, const int* __restrict__ cn,
                           float* __restrict__ sC6, float* __restrict__ qR, int n_nodes) {
    int i = blockIdx.x * blockDim.x + threadIdx.x;
    if (i >= n_nodes) return;
    int z = Z[i];
    float R, C6;
    if (z == 6) {          // carbon: sp2 vs sp3 by coordination
        if (cn[i] <= 3) { R = 2.2348f; C6 = 429.69f; }
        else            { R = 1.8219f; C6 = 184.28f; }
    } else if (z == 7) {   // nitrogen
        if (cn[i] <= 2) { R = 2.6454f; C6 = 720.18f; }
        else            { R = 2.4667f; C6 = 482.54f; }
    } else {
        float2 rc = GNB_RC6[z];
        R = rc.x; C6 = rc.y;
    }
    sC6[i] = sqrtf(C6);
    qR[i]  = sqrtf(sqrtf(R));
}

__device__ __forceinline__ void gnb_edge_one(int s, int rcv, float r,
                                             const float* __restrict__ sC6,
                                             const float* __restrict__ qR,
                                             float* __restrict__ out) {
    // envelope: 1 for r<8, poly on x=(r-8)/2 for 8<=r<10, 0 for r>=10
    float env;
    if (r < 8.0f) {
        env = 1.0f;
    } else {
        float x = (r - 8.0f) * 0.5f;
        if (x < 1.0f) {
            float x2 = x * x;
            float x3 = x2 * x;
            float x6 = x3 * x3;
            env = 1.0f - 28.0f * x6 + 48.0f * x6 * x - 21.0f * x6 * x2;
        } else {
            env = 0.0f;   // contribution is exactly 0 -> skip atomic
            return;
        }
    }
    float sRij = qR[s] * qR[rcv];       // sqrt(R_ij)
    float C6ij = sC6[s] * sC6[rcv];     // sqrt(C6_s * C6_r)
    float Rij  = sRij * sRij;
    float Rij3 = Rij * Rij * Rij;
    float R6   = Rij3 * Rij3;           // R_ij^6
    float r0   = 0.4f * sRij + 4.0f;
    float t    = r0 / r;
    float t2 = t * t, t4 = t2 * t2, t8 = t4 * t4;
    float t14 = t8 * t4 * t2;
    float fd = 1.0f / (1.0f + 6.0f * t14);
    float r2 = r * r;
    float r6 = r2 * r2 * r2;
    float e = -C6ij / (R6 + r6) * fd * env;
    atomicAdd(&out[rcv], 0.5f * e);
}

__global__ void gnb_edges(const int* __restrict__ send, const int* __restrict__ recv,
                          const float* __restrict__ len,
                          const float* __restrict__ sC6, const float* __restrict__ qR,
                          float* __restrict__ out, int n_edges) {
    int i = blockIdx.x * blockDim.x + threadIdx.x;
    int base = i * 4;
    if (base + 3 < n_edges) {
        int4   s4 = *(const int4*)(send + base);
        int4   r4 = *(const int4*)(recv + base);
        float4 l4 = *(const float4*)(len + base);
        gnb_edge_one(s4.x, r4.x, l4.x, sC6, qR, out);
        gnb_edge_one(s4.y, r4.y, l4.y, sC6, qR, out);
        gnb_edge_one(s4.z, r4.z, l4.z, sC6, qR, out);
        gnb_edge_one(s4.w, r4.w, l4.w, sC6, qR, out);
    } else {
        for (int e = base; e < n_edges; ++e)
            gnb_edge_one(send[e], recv[e], len[e], sC6, qR, out);
    }
}

extern "C" void kernel_launch(void* const* d_in, const int* in_sizes, int n_in,
                              void* d_out, int out_size, void* d_ws, size_t ws_size,
                              hipStream_t stream) {
    const int*   Z    = (const int*)d_in[0];
    const int*   eidx = (const int*)d_in[1];
    const float* len  = (const float*)d_in[2];
    float*       out  = (float*)d_out;

    const int n_nodes = in_sizes[0];
    const int n_edges = in_sizes[2];
    const int* send = eidx;
    const int* recv = eidx + n_edges;

    char* ws = (char*)d_ws;
    int*   cn  = (int*)ws;
    float* sC6 = (float*)(ws + (size_t)n_nodes * 4);
    float* qR  = (float*)(ws + (size_t)n_nodes * 8);

    const int B = 256;
    int node_blocks = (n_nodes + B - 1) / B;
    int edge_vec    = (n_edges + 3) / 4;
    int edge_blocks = (edge_vec + B - 1) / B;

    gnb_init<<<node_blocks, B, 0, stream>>>(out, cn, n_nodes);
    gnb_degree<<<edge_blocks, B, 0, stream>>>(recv, cn, n_edges);
    gnb_params<<<node_blocks, B, 0, stream>>>(Z, cn, sC6, qR, n_nodes);
    gnb_edges<<<edge_blocks, B, 0, stream>>>(send, recv, len, sC6, qR, out, n_edges);
}

// Round 2
// 640.195 us; speedup vs baseline: 1.0348x; 1.0348x over previous
//
#include <hip/hip_runtime.h>

// GNB dispersion-energy graph kernel — Round 2: replicated atomic accumulators.
// Inputs: d_in[0]=Z int32[n_nodes], d_in[1]=edge_index int32[2,n_edges],
//         d_in[2]=lengths f32[n_edges]. Output: node_energy f32[n_nodes].
//
// ws layout (R replicas): [cnrep: int32 R*n] [outrep: f32 R*n] [sC6: f32 n] [qR: f32 n]

__device__ __constant__ float2 GNB_RC6[87] = {
    {0.f, 0.f},
    {3.6516f, 95.99f},   {2.1843f, 40.67f},   {1.2711f, 70.21f},
    {3.3497f, 114.51f},  {2.7079f, 152.36f},  {1.8219f, 184.28f},
    {2.4667f, 482.54f},  {2.365f, 405.57f},   {1.5062f, 218.45f},
    {1.8233f, 174.81f},  {1.3974f, 181.7f},   {3.3515f, 263.02f},
    {3.0102f, 228.1f},   {3.1629f, 359.43f},  {3.2554f, 3222.12f},
    {2.9539f, 2144.49f}, {3.0368f, 2072.46f}, {2.6598f, 1357.42f},
    {4.0877f, 1406.65f}, {4.1275f, 1058.36f}, {9.7282f, 11498.73f},
    {8.5322f, 3361.33f}, {7.2344f, 2095.91f}, {5.3605f, 1049.31f},
    {3.718f, 966.27f},   {3.6408f, 1571.36f}, {3.4961f, 1183.59f},
    {3.5108f, 787.76f},  {3.0537f, 563.93f},  {3.0261f, 592.91f},
    {3.1735f, 430.82f},  {3.1773f, 812.57f},  {3.8357f, 4533.53f},
    {3.1109f, 3440.92f}, {3.2122f, 3859.82f}, {2.8263f, 2729.6f},
    {2.412f, 1864.19f},  {1.894f, 1175.73f},  {11.2061f, 32141.18f},
    {6.821f, 27655.14f}, {7.2367f, 2864.2f},  {3.901f, 3563.45f},
    {4.0857f, 3266.43f}, {4.045f, 3967.23f},  {3.4813f, 2233.82f},
    {3.0487f, 1393.49f}, {2.7795f, 1315.09f}, {2.8673f, 1311.47f},
    {3.3339f, 1460.56f}, {3.0086f, 1662.99f}, {3.9919f, 8089.97f},
    {3.4209f, 6887.05f}, {3.5649f, 8799.32f}, {3.0288f, 6136.5f},
    {2.262f, 3757.31f},  {1.3837f, 2561.18f}, {12.171f, 66580.83f},
    {0.f,0.f},{0.f,0.f},{0.f,0.f},{0.f,0.f},{0.f,0.f},{0.f,0.f},{0.f,0.f},
    {0.f,0.f},{0.f,0.f},{0.f,0.f},{0.f,0.f},{0.f,0.f},{0.f,0.f},{0.f,0.f},
    {6.0791f, 27593.76f}, {5.7661f, 15364.65f}, {3.6366f, 2734.5f},
    {4.241f, 4801.82f},   {4.1348f, 5685.94f},  {3.4213f, 2786.0f},
    {3.2486f, 2699.79f},  {2.9588f, 2282.6f},   {2.9381f, 2476.79f},
    {2.7711f, 2988.7f},   {2.5816f, 2506.63f},  {3.785f, 8916.84f},
    {3.5381f, 8694.22f},  {3.6985f, 11821.61f}, {3.0551f, 8410.64f},
};

// Zero `n` 32-bit words (grid-stride).
__global__ void gnb_zero(int* __restrict__ p, int n) {
    int stride = gridDim.x * blockDim.x;
    for (int i = blockIdx.x * blockDim.x + threadIdx.x; i < n; i += stride)
        p[i] = 0;
}

__global__ void gnb_degree_rep(const int* __restrict__ recv, int* __restrict__ cnrep,
                               int n_edges, int n_nodes, int R) {
    int i = blockIdx.x * blockDim.x + threadIdx.x;
    int* cn = cnrep + (size_t)((i >> 6) % R) * n_nodes;  // per-wave replica
    int base = i * 4;
    if (base + 3 < n_edges) {
        int4 r = *(const int4*)(recv + base);
        atomicAdd(&cn[r.x], 1);
        atomicAdd(&cn[r.y], 1);
        atomicAdd(&cn[r.z], 1);
        atomicAdd(&cn[r.w], 1);
    } else {
        for (int e = base; e < n_edges; ++e) atomicAdd(&cn[recv[e]], 1);
    }
}

// Sum cn replicas; compute sC6 = sqrt(C6_i), qR = R_i^(1/4).
__global__ void gnb_params(const int* __restrict__ Z, const int* __restrict__ cnrep,
                           float* __restrict__ sC6, float* __restrict__ qR,
                           int n_nodes, int R) {
    int i = blockIdx.x * blockDim.x + threadIdx.x;
    if (i >= n_nodes) return;
    int z = Z[i];
    float Rp, C6;
    if (z == 6 || z == 7) {
        int cn = 0;
        for (int r = 0; r < R; ++r) cn += cnrep[(size_t)r * n_nodes + i];
        if (z == 6) {   // carbon: sp2 vs sp3
            if (cn <= 3) { Rp = 2.2348f; C6 = 429.69f; }
            else         { Rp = 1.8219f; C6 = 184.28f; }
        } else {        // nitrogen
            if (cn <= 2) { Rp = 2.6454f; C6 = 720.18f; }
            else         { Rp = 2.4667f; C6 = 482.54f; }
        }
    } else {
        float2 rc = GNB_RC6[z];
        Rp = rc.x; C6 = rc.y;
    }
    sC6[i] = sqrtf(C6);
    qR[i]  = sqrtf(sqrtf(Rp));
}

__device__ __forceinline__ void gnb_edge_one(int s, int rcv, float r,
                                             const float* __restrict__ sC6,
                                             const float* __restrict__ qR,
                                             float* __restrict__ out) {
    float env;
    if (r < 8.0f) {
        env = 1.0f;
    } else {
        float x = (r - 8.0f) * 0.5f;
        if (x < 1.0f) {
            float x2 = x * x;
            float x3 = x2 * x;
            float x6 = x3 * x3;
            env = 1.0f - 28.0f * x6 + 48.0f * x6 * x - 21.0f * x6 * x2;
        } else {
            return;  // exact zero contribution
        }
    }
    float sRij = qR[s] * qR[rcv];       // sqrt(R_ij)
    float C6ij = sC6[s] * sC6[rcv];     // sqrt(C6_s*C6_r)
    float Rij  = sRij * sRij;
    float Rij3 = Rij * Rij * Rij;
    float R6   = Rij3 * Rij3;
    float r0   = 0.4f * sRij + 4.0f;
    float t    = r0 / r;
    float t2 = t * t, t4 = t2 * t2, t8 = t4 * t4;
    float t14 = t8 * t4 * t2;
    float fd = 1.0f / (1.0f + 6.0f * t14);
    float r2 = r * r;
    float r6 = r2 * r2 * r2;
    float e = -C6ij / (R6 + r6) * fd * env;
    atomicAdd(&out[rcv], 0.5f * e);
}

__global__ void gnb_edges_rep(const int* __restrict__ send, const int* __restrict__ recv,
                              const float* __restrict__ len,
                              const float* __restrict__ sC6, const float* __restrict__ qR,
                              float* __restrict__ outrep, int n_edges, int n_nodes, int R) {
    int i = blockIdx.x * blockDim.x + threadIdx.x;
    float* out = outrep + (size_t)((i >> 6) % R) * n_nodes;  // per-wave replica
    int base = i * 4;
    if (base + 3 < n_edges) {
        int4   s4 = *(const int4*)(send + base);
        int4   r4 = *(const int4*)(recv + base);
        float4 l4 = *(const float4*)(len + base);
        gnb_edge_one(s4.x, r4.x, l4.x, sC6, qR, out);
        gnb_edge_one(s4.y, r4.y, l4.y, sC6, qR, out);
        gnb_edge_one(s4.z, r4.z, l4.z, sC6, qR, out);
        gnb_edge_one(s4.w, r4.w, l4.w, sC6, qR, out);
    } else {
        for (int e = base; e < n_edges; ++e)
            gnb_edge_one(send[e], recv[e], len[e], sC6, qR, out);
    }
}

__global__ void gnb_reduce_out(const float* __restrict__ outrep, float* __restrict__ out,
                               int n_nodes, int R) {
    int i = blockIdx.x * blockDim.x + threadIdx.x;
    if (i >= n_nodes) return;
    float s = 0.0f;
    for (int r = 0; r < R; ++r) s += outrep[(size_t)r * n_nodes + i];
    out[i] = s;
}

extern "C" void kernel_launch(void* const* d_in, const int* in_sizes, int n_in,
                              void* d_out, int out_size, void* d_ws, size_t ws_size,
                              hipStream_t stream) {
    const int*   Z    = (const int*)d_in[0];
    const int*   eidx = (const int*)d_in[1];
    const float* len  = (const float*)d_in[2];
    float*       out  = (float*)d_out;

    const int n_nodes = in_sizes[0];
    const int n_edges = in_sizes[2];
    const int* send = eidx;
    const int* recv = eidx + n_edges;

    // Pick replica count from available workspace: need (2R + 2) * n_nodes words.
    size_t words = ws_size / 4;
    int R = (int)((words / (size_t)n_nodes - 2) / 2);
    if (R > 16) R = 16;
    if (R < 1)  R = 1;

    char* ws = (char*)d_ws;
    int*   cnrep  = (int*)ws;
    float* outrep = (float*)(ws + (size_t)R * n_nodes * 4);
    float* sC6    = (float*)(ws + (size_t)2 * R * n_nodes * 4);
    float* qR     = (float*)(ws + (size_t)(2 * R + 1) * n_nodes * 4);

    const int B = 256;
    int node_blocks = (n_nodes + B - 1) / B;
    int edge_vec    = (n_edges + 3) / 4;
    int edge_blocks = (edge_vec + B - 1) / B;
    int zero_words  = 2 * R * n_nodes;

    gnb_zero<<<1024, B, 0, stream>>>((int*)ws, zero_words);
    gnb_degree_rep<<<edge_blocks, B, 0, stream>>>(recv, cnrep, n_edges, n_nodes, R);
    gnb_params<<<node_blocks, B, 0, stream>>>(Z, cnrep, sC6, qR, n_nodes, R);
    gnb_edges_rep<<<edge_blocks, B, 0, stream>>>(send, recv, len, sC6, qR, outrep,
                                                 n_edges, n_nodes, R);
    gnb_reduce_out<<<node_blocks, B, 0, stream>>>(outrep, out, n_nodes, R);
}

// Round 3
// 278.113 us; speedup vs baseline: 2.3820x; 2.3019x over previous
//
#include <hip/hip_runtime.h>

// GNB dispersion-energy graph kernel — Round 3: kill device-scope atomics.
//   * degree pass: atomic only when Z[recv] is C/N (~2.3% of edges)
//   * energy pass: LDS-binned accumulation (7 bins x 16384 nodes x 64KB LDS),
//     replica stores + tree reduce — zero global atomics
// Inputs: d_in[0]=Z int32[n_nodes], d_in[1]=edge_index int32[2,n_edges],
//         d_in[2]=lengths f32[n_edges]. Output: node_energy f32[n_nodes].
// ws: [cn int32 n][P2 float2 n][repbuf f32 NB*BPB*BINSZ]

#define LBITS 14
#define BINSZ 16384            // nodes per bin (64KB fp32 LDS)
#define EBLOCK 512             // threads per binned block

__device__ __constant__ float2 GNB_RC6[87] = {
    {0.f, 0.f},
    {3.6516f, 95.99f},   {2.1843f, 40.67f},   {1.2711f, 70.21f},
    {3.3497f, 114.51f},  {2.7079f, 152.36f},  {1.8219f, 184.28f},
    {2.4667f, 482.54f},  {2.365f, 405.57f},   {1.5062f, 218.45f},
    {1.8233f, 174.81f},  {1.3974f, 181.7f},   {3.3515f, 263.02f},
    {3.0102f, 228.1f},   {3.1629f, 359.43f},  {3.2554f, 3222.12f},
    {2.9539f, 2144.49f}, {3.0368f, 2072.46f}, {2.6598f, 1357.42f},
    {4.0877f, 1406.65f}, {4.1275f, 1058.36f}, {9.7282f, 11498.73f},
    {8.5322f, 3361.33f}, {7.2344f, 2095.91f}, {5.3605f, 1049.31f},
    {3.718f, 966.27f},   {3.6408f, 1571.36f}, {3.4961f, 1183.59f},
    {3.5108f, 787.76f},  {3.0537f, 563.93f},  {3.0261f, 592.91f},
    {3.1735f, 430.82f},  {3.1773f, 812.57f},  {3.8357f, 4533.53f},
    {3.1109f, 3440.92f}, {3.2122f, 3859.82f}, {2.8263f, 2729.6f},
    {2.412f, 1864.19f},  {1.894f, 1175.73f},  {11.2061f, 32141.18f},
    {6.821f, 27655.14f}, {7.2367f, 2864.2f},  {3.901f, 3563.45f},
    {4.0857f, 3266.43f}, {4.045f, 3967.23f},  {3.4813f, 2233.82f},
    {3.0487f, 1393.49f}, {2.7795f, 1315.09f}, {2.8673f, 1311.47f},
    {3.3339f, 1460.56f}, {3.0086f, 1662.99f}, {3.9919f, 8089.97f},
    {3.4209f, 6887.05f}, {3.5649f, 8799.32f}, {3.0288f, 6136.5f},
    {2.262f, 3757.31f},  {1.3837f, 2561.18f}, {12.171f, 66580.83f},
    {0.f,0.f},{0.f,0.f},{0.f,0.f},{0.f,0.f},{0.f,0.f},{0.f,0.f},{0.f,0.f},
    {0.f,0.f},{0.f,0.f},{0.f,0.f},{0.f,0.f},{0.f,0.f},{0.f,0.f},{0.f,0.f},
    {6.0791f, 27593.76f}, {5.7661f, 15364.65f}, {3.6366f, 2734.5f},
    {4.241f, 4801.82f},   {4.1348f, 5685.94f},  {3.4213f, 2786.0f},
    {3.2486f, 2699.79f},  {2.9588f, 2282.6f},   {2.9381f, 2476.79f},
    {2.7711f, 2988.7f},   {2.5816f, 2506.63f},  {3.785f, 8916.84f},
    {3.5381f, 8694.22f},  {3.6985f, 11821.61f}, {3.0551f, 8410.64f},
};

__global__ void gnb_zero(int* __restrict__ p, int n) {
    int stride = gridDim.x * blockDim.x;
    for (int i = blockIdx.x * blockDim.x + threadIdx.x; i < n; i += stride)
        p[i] = 0;
}

// Degree, filtered: only C/N receivers ever consume cn.
__global__ void gnb_degree_cn(const int* __restrict__ recv, const int* __restrict__ Z,
                              int* __restrict__ cn, int n_edges) {
    int i = blockIdx.x * blockDim.x + threadIdx.x;
    int base = i * 4;
    if (base + 3 < n_edges) {
        int4 r = *(const int4*)(recv + base);
        int zx = Z[r.x], zy = Z[r.y], zz = Z[r.z], zw = Z[r.w];
        if (zx == 6 || zx == 7) atomicAdd(&cn[r.x], 1);
        if (zy == 6 || zy == 7) atomicAdd(&cn[r.y], 1);
        if (zz == 6 || zz == 7) atomicAdd(&cn[r.z], 1);
        if (zw == 6 || zw == 7) atomicAdd(&cn[r.w], 1);
    } else {
        for (int e = base; e < n_edges; ++e) {
            int rr = recv[e];
            int z = Z[rr];
            if (z == 6 || z == 7) atomicAdd(&cn[rr], 1);
        }
    }
}

// P2[i] = {sqrt(C6_i), R_i^(1/4)} — one 8B gather per endpoint in the edge pass.
__global__ void gnb_params(const int* __restrict__ Z, const int* __restrict__ cn,
                           float2* __restrict__ P2, int n_nodes) {
    int i = blockIdx.x * blockDim.x + threadIdx.x;
    if (i >= n_nodes) return;
    int z = Z[i];
    float Rp, C6;
    if (z == 6) {
        if (cn[i] <= 3) { Rp = 2.2348f; C6 = 429.69f; }
        else            { Rp = 1.8219f; C6 = 184.28f; }
    } else if (z == 7) {
        if (cn[i] <= 2) { Rp = 2.6454f; C6 = 720.18f; }
        else            { Rp = 2.4667f; C6 = 482.54f; }
    } else {
        float2 rc = GNB_RC6[z];
        Rp = rc.x; C6 = rc.y;
    }
    P2[i] = make_float2(sqrtf(C6), sqrtf(sqrtf(Rp)));
}

__device__ __forceinline__ void gnb_edge_lds(int s, int r, float rlen, int bin,
                                             const float2* __restrict__ P2,
                                             float* __restrict__ acc) {
    if ((r >> LBITS) != bin) return;
    float env;
    if (rlen < 8.0f) {
        env = 1.0f;
    } else {
        float x = (rlen - 8.0f) * 0.5f;
        if (x >= 1.0f) return;               // exact zero
        float x2 = x * x;
        float x6 = x2 * x2 * x2;
        env = 1.0f - 28.0f * x6 + 48.0f * x6 * x - 21.0f * x6 * x2;
    }
    float2 ps = P2[s];
    float2 pr = P2[r];
    float sRij = ps.y * pr.y;                // sqrt(R_ij)
    float C6ij = ps.x * pr.x;                // sqrt(C6_s*C6_r)
    float Rij  = sRij * sRij;
    float Rij3 = Rij * Rij * Rij;
    float R6   = Rij3 * Rij3;
    float r0   = 0.4f * sRij + 4.0f;
    float t    = r0 / rlen;
    float t2 = t * t, t4 = t2 * t2, t8 = t4 * t4;
    float t14 = t8 * t4 * t2;
    float fd = 1.0f / (1.0f + 6.0f * t14);
    float rl2 = rlen * rlen;
    float r6 = rl2 * rl2 * rl2;
    float e = -C6ij / (R6 + r6) * fd * env;
    atomicAdd(&acc[r & (BINSZ - 1)], 0.5f * e);
}

// One block = (bin, edge-slice replica). Accumulate in LDS, store bin to repbuf.
__global__ void __launch_bounds__(EBLOCK)
gnb_energy_binned(const int* __restrict__ send, const int* __restrict__ recv,
                  const float* __restrict__ len, const float2* __restrict__ P2,
                  float* __restrict__ repbuf, int n_edges, int BPB, int slice4) {
    __shared__ float acc[BINSZ];
    const int bin = blockIdx.x / BPB;
    const int rep = blockIdx.x % BPB;
    const int tid = threadIdx.x;

    for (int o = tid; o < BINSZ; o += EBLOCK) acc[o] = 0.0f;
    __syncthreads();

    int e0 = rep * slice4;
    int e_end = e0 + slice4;
    if (e_end > n_edges) e_end = n_edges;

    for (int base = e0 + tid * 4; base < e_end; base += EBLOCK * 4) {
        if (base + 3 < e_end) {
            int4   s4 = *(const int4*)(send + base);
            int4   r4 = *(const int4*)(recv + base);
            float4 l4 = *(const float4*)(len + base);
            gnb_edge_lds(s4.x, r4.x, l4.x, bin, P2, acc);
            gnb_edge_lds(s4.y, r4.y, l4.y, bin, P2, acc);
            gnb_edge_lds(s4.z, r4.z, l4.z, bin, P2, acc);
            gnb_edge_lds(s4.w, r4.w, l4.w, bin, P2, acc);
        } else {
            for (int e = base; e < e_end; ++e)
                gnb_edge_lds(send[e], recv[e], len[e], bin, P2, acc);
        }
    }
    __syncthreads();

    float* dst = repbuf + (size_t)blockIdx.x * BINSZ;
    for (int o = tid; o < BINSZ; o += EBLOCK) dst[o] = acc[o];
}

__global__ void gnb_reduce_out(const float* __restrict__ repbuf, float* __restrict__ out,
                               int n_nodes, int BPB) {
    int i = blockIdx.x * blockDim.x + threadIdx.x;
    if (i >= n_nodes) return;
    int b = i >> LBITS;
    int o = i & (BINSZ - 1);
    const float* src = repbuf + ((size_t)b * BPB) * BINSZ + o;
    float s = 0.0f;
    for (int p = 0; p < BPB; ++p) s += src[(size_t)p * BINSZ];
    out[i] = s;
}

extern "C" void kernel_launch(void* const* d_in, const int* in_sizes, int n_in,
                              void* d_out, int out_size, void* d_ws, size_t ws_size,
                              hipStream_t stream) {
    const int*   Z    = (const int*)d_in[0];
    const int*   eidx = (const int*)d_in[1];
    const float* len  = (const float*)d_in[2];
    float*       out  = (float*)d_out;

    const int n_nodes = in_sizes[0];
    const int n_edges = in_sizes[2];
    const int* send = eidx;
    const int* recv = eidx + n_edges;

    const int NB = (n_nodes + BINSZ - 1) / BINSZ;   // bins

    char* ws = (char*)d_ws;
    int*    cn     = (int*)ws;
    float2* P2     = (float2*)(ws + (size_t)n_nodes * 4);
    float*  repbuf = (float*)(ws + (size_t)n_nodes * 12);

    // Replicas per bin, bounded by workspace; target grid ~2 blocks/CU.
    size_t avail = (ws_size > (size_t)n_nodes * 12) ? ws_size - (size_t)n_nodes * 12 : 0;
    int BPB = (int)(avail / ((size_t)NB * BINSZ * 4));
    if (BPB > 73) BPB = 73;
    if (BPB < 1)  BPB = 1;

    int slice  = (n_edges + BPB - 1) / BPB;
    int slice4 = ((slice + 3) / 4) * 4;             // keep int4 slices aligned

    const int B = 256;
    int node_blocks = (n_nodes + B - 1) / B;
    int edge_vec    = (n_edges + 3) / 4;
    int edge_blocks = (edge_vec + B - 1) / B;

    gnb_zero<<<256, B, 0, stream>>>(cn, n_nodes);
    gnb_degree_cn<<<edge_blocks, B, 0, stream>>>(recv, Z, cn, n_edges);
    gnb_params<<<node_blocks, B, 0, stream>>>(Z, cn, P2, n_nodes);
    gnb_energy_binned<<<NB * BPB, EBLOCK, 0, stream>>>(send, recv, len, P2, repbuf,
                                                       n_edges, BPB, slice4);
    gnb_reduce_out<<<node_blocks, B, 0, stream>>>(repbuf, out, n_nodes, BPB);
}

// Round 4
// 252.160 us; speedup vs baseline: 2.6272x; 1.1029x over previous
//
#include <hip/hip_runtime.h>

// GNB dispersion-energy graph kernel — Round 4: scatter/gather, each edge touched once.
//   1. degree (filtered: only C/N receivers, ~2.3% of edges atomic)
//   2. params: P2[i] = {sqrt(C6_i), R_i^(1/4)}
//   3. scatter: stream edges once, compute c = 0.5*e_edge, route {r,c} records
//      into 98 per-bin buckets (1024 nodes/bin) via LDS histogram + cursor bump
//   4. gather: per (bin,slice) block accumulates its record range in 4KB LDS
//   5. reduce: out = ovf + sum of slice replicas
// Assumes n_nodes <= 131072 (key packs r into 17 bits) and NB2 <= 128.
// ws: [cn int32 n][cursor u32 128][ovf f32 n][P2 float2 n][rep f32 NB2*SLICES*1024][buckets uint2 NB2*cap]

#define B2SHIFT 10
#define B2SIZE  1024
#define TILE    4096      // edges per scatter block (256 thr x 16)
#define SLICES  16
#define MAXB    128

__device__ __constant__ float2 GNB_RC6[87] = {
    {0.f, 0.f},
    {3.6516f, 95.99f},   {2.1843f, 40.67f},   {1.2711f, 70.21f},
    {3.3497f, 114.51f},  {2.7079f, 152.36f},  {1.8219f, 184.28f},
    {2.4667f, 482.54f},  {2.365f, 405.57f},   {1.5062f, 218.45f},
    {1.8233f, 174.81f},  {1.3974f, 181.7f},   {3.3515f, 263.02f},
    {3.0102f, 228.1f},   {3.1629f, 359.43f},  {3.2554f, 3222.12f},
    {2.9539f, 2144.49f}, {3.0368f, 2072.46f}, {2.6598f, 1357.42f},
    {4.0877f, 1406.65f}, {4.1275f, 1058.36f}, {9.7282f, 11498.73f},
    {8.5322f, 3361.33f}, {7.2344f, 2095.91f}, {5.3605f, 1049.31f},
    {3.718f, 966.27f},   {3.6408f, 1571.36f}, {3.4961f, 1183.59f},
    {3.5108f, 787.76f},  {3.0537f, 563.93f},  {3.0261f, 592.91f},
    {3.1735f, 430.82f},  {3.1773f, 812.57f},  {3.8357f, 4533.53f},
    {3.1109f, 3440.92f}, {3.2122f, 3859.82f}, {2.8263f, 2729.6f},
    {2.412f, 1864.19f},  {1.894f, 1175.73f},  {11.2061f, 32141.18f},
    {6.821f, 27655.14f}, {7.2367f, 2864.2f},  {3.901f, 3563.45f},
    {4.0857f, 3266.43f}, {4.045f, 3967.23f},  {3.4813f, 2233.82f},
    {3.0487f, 1393.49f}, {2.7795f, 1315.09f}, {2.8673f, 1311.47f},
    {3.3339f, 1460.56f}, {3.0086f, 1662.99f}, {3.9919f, 8089.97f},
    {3.4209f, 6887.05f}, {3.5649f, 8799.32f}, {3.0288f, 6136.5f},
    {2.262f, 3757.31f},  {1.3837f, 2561.18f}, {12.171f, 66580.83f},
    {0.f,0.f},{0.f,0.f},{0.f,0.f},{0.f,0.f},{0.f,0.f},{0.f,0.f},{0.f,0.f},
    {0.f,0.f},{0.f,0.f},{0.f,0.f},{0.f,0.f},{0.f,0.f},{0.f,0.f},{0.f,0.f},
    {6.0791f, 27593.76f}, {5.7661f, 15364.65f}, {3.6366f, 2734.5f},
    {4.241f, 4801.82f},   {4.1348f, 5685.94f},  {3.4213f, 2786.0f},
    {3.2486f, 2699.79f},  {2.9588f, 2282.6f},   {2.9381f, 2476.79f},
    {2.7711f, 2988.7f},   {2.5816f, 2506.63f},  {3.785f, 8916.84f},
    {3.5381f, 8694.22f},  {3.6985f, 11821.61f}, {3.0551f, 8410.64f},
};

__global__ void gnb_zero(int* __restrict__ p, int n) {
    int stride = gridDim.x * blockDim.x;
    for (int i = blockIdx.x * blockDim.x + threadIdx.x; i < n; i += stride)
        p[i] = 0;
}

__global__ void gnb_degree_cn(const int* __restrict__ recv, const int* __restrict__ Z,
                              int* __restrict__ cn, int n_edges) {
    int i = blockIdx.x * blockDim.x + threadIdx.x;
    int base = i * 4;
    if (base + 3 < n_edges) {
        int4 r = *(const int4*)(recv + base);
        int zx = Z[r.x], zy = Z[r.y], zz = Z[r.z], zw = Z[r.w];
        if (zx == 6 || zx == 7) atomicAdd(&cn[r.x], 1);
        if (zy == 6 || zy == 7) atomicAdd(&cn[r.y], 1);
        if (zz == 6 || zz == 7) atomicAdd(&cn[r.z], 1);
        if (zw == 6 || zw == 7) atomicAdd(&cn[r.w], 1);
    } else {
        for (int e = base; e < n_edges; ++e) {
            int rr = recv[e];
            int z = Z[rr];
            if (z == 6 || z == 7) atomicAdd(&cn[rr], 1);
        }
    }
}

__global__ void gnb_params(const int* __restrict__ Z, const int* __restrict__ cn,
                           float2* __restrict__ P2, int n_nodes) {
    int i = blockIdx.x * blockDim.x + threadIdx.x;
    if (i >= n_nodes) return;
    int z = Z[i];
    float Rp, C6;
    if (z == 6) {
        if (cn[i] <= 3) { Rp = 2.2348f; C6 = 429.69f; }
        else            { Rp = 1.8219f; C6 = 184.28f; }
    } else if (z == 7) {
        if (cn[i] <= 2) { Rp = 2.6454f; C6 = 720.18f; }
        else            { Rp = 2.4667f; C6 = 482.54f; }
    } else {
        float2 rc = GNB_RC6[z];
        Rp = rc.x; C6 = rc.y;
    }
    P2[i] = make_float2(sqrtf(C6), sqrtf(sqrtf(Rp)));
}

// c = 0.5 * e_edge (envelope folded in). Returns false iff contribution is exactly 0.
__device__ __forceinline__ bool gnb_edge_energy(int s, int r, float rlen,
                                                const float2* __restrict__ P2,
                                                float& c) {
    float env;
    if (rlen < 8.0f) {
        env = 1.0f;
    } else {
        float x = (rlen - 8.0f) * 0.5f;
        if (x >= 1.0f) return false;
        float x2 = x * x;
        float x6 = x2 * x2 * x2;
        env = 1.0f - 28.0f * x6 + 48.0f * x6 * x - 21.0f * x6 * x2;
    }
    float2 ps = P2[s];
    float2 pr = P2[r];
    float sR  = ps.y * pr.y;            // sqrt(R_ij)
    float C6  = ps.x * pr.x;            // sqrt(C6_s*C6_r)
    float Rij = sR * sR;
    float R3  = Rij * Rij * Rij;
    float R6  = R3 * R3;
    float r0  = 0.4f * sR + 4.0f;
    float t   = r0 / rlen;
    float t2 = t * t, t4 = t2 * t2, t8 = t4 * t4;
    float t14 = t8 * t4 * t2;
    float fd = 1.0f / (1.0f + 6.0f * t14);
    float rl2 = rlen * rlen;
    float r6 = rl2 * rl2 * rl2;
    c = -0.5f * C6 / (R6 + r6) * fd * env;
    return true;
}

// One block = one tile of TILE edges. Compute c, assign per-bin ranks via LDS
// histogram, bump 98 global cursors once, store {r, c} records to bin buckets.
__global__ void __launch_bounds__(256)
gnb_scatter(const int* __restrict__ send, const int* __restrict__ recv,
            const float* __restrict__ len, const float2* __restrict__ P2,
            uint2* __restrict__ buckets, unsigned* __restrict__ cursor,
            float* __restrict__ ovf, int n_edges, int cap, int NB2) {
    __shared__ unsigned cnt[MAXB];
    __shared__ unsigned gbase[MAXB];
    const int tid = threadIdx.x;
    const int e0  = blockIdx.x * TILE;

    for (int b = tid; b < MAXB; b += 256) cnt[b] = 0;
    __syncthreads();

    unsigned key[16];   // r | rank<<17 ; 0xFFFFFFFF = invalid
    float    val[16];

    #pragma unroll
    for (int k = 0; k < 4; ++k) {
        int base = e0 + (k * 256 + tid) * 4;
        int s4[4], r4[4]; float l4[4];
        int nv = 0;
        if (base + 3 < n_edges) {
            int4   sv = *(const int4*)(send + base);
            int4   rv = *(const int4*)(recv + base);
            float4 lv = *(const float4*)(len + base);
            s4[0]=sv.x; s4[1]=sv.y; s4[2]=sv.z; s4[3]=sv.w;
            r4[0]=rv.x; r4[1]=rv.y; r4[2]=rv.z; r4[3]=rv.w;
            l4[0]=lv.x; l4[1]=lv.y; l4[2]=lv.z; l4[3]=lv.w;
            nv = 4;
        } else {
            for (int e = base; e < n_edges; ++e) {
                s4[nv] = send[e]; r4[nv] = recv[e]; l4[nv] = len[e]; ++nv;
            }
        }
        #pragma unroll
        for (int j = 0; j < 4; ++j) {
            int idx = k * 4 + j;
            key[idx] = 0xFFFFFFFFu;
            if (j < nv) {
                float c;
                if (gnb_edge_energy(s4[j], r4[j], l4[j], P2, c)) {
                    unsigned r = (unsigned)r4[j];
                    unsigned rank = atomicAdd(&cnt[r >> B2SHIFT], 1u);
                    key[idx] = r | (rank << 17);
                    val[idx] = c;
                }
            }
        }
    }
    __syncthreads();
    if (tid < NB2) gbase[tid] = atomicAdd(&cursor[tid], cnt[tid]);
    __syncthreads();

    #pragma unroll
    for (int i = 0; i < 16; ++i) {
        unsigned kk = key[i];
        if (kk == 0xFFFFFFFFu) continue;
        unsigned r    = kk & 0x1FFFFu;
        unsigned rank = kk >> 17;
        unsigned b    = r >> B2SHIFT;
        unsigned slot = gbase[b] + rank;
        if (slot < (unsigned)cap)
            buckets[(size_t)b * cap + slot] = make_uint2(r, __float_as_uint(val[i]));
        else
            atomicAdd(&ovf[r], val[i]);   // graceful overflow (small/absent ws)
    }
}

// One block = (bin, slice). Read its contiguous record range once, LDS-accumulate,
// store a replica (no global atomics).
__global__ void __launch_bounds__(256)
gnb_gather(const uint2* __restrict__ buckets, const unsigned* __restrict__ cursor,
           float* __restrict__ rep, int cap) {
    __shared__ float acc[B2SIZE];
    const int b   = blockIdx.x / SLICES;
    const int s   = blockIdx.x % SLICES;
    const int tid = threadIdx.x;

    for (int i = tid; i < B2SIZE; i += 256) acc[i] = 0.0f;
    __syncthreads();

    unsigned count = cursor[b];
    if (count > (unsigned)cap) count = (unsigned)cap;
    unsigned seg = (count + SLICES - 1) / SLICES;
    unsigned st  = (unsigned)s * seg;
    unsigned en  = st + seg; if (en > count) en = count;

    const uint2* src = buckets + (size_t)b * cap;
    for (unsigned i = st + tid; i < en; i += 256) {
        uint2 rec = src[i];
        atomicAdd(&acc[rec.x & (B2SIZE - 1)], __uint_as_float(rec.y));
    }
    __syncthreads();

    float* dst = rep + (size_t)blockIdx.x * B2SIZE;
    for (int i = tid; i < B2SIZE; i += 256) dst[i] = acc[i];
}

__global__ void gnb_reduce(const float* __restrict__ rep, const float* __restrict__ ovf,
                           float* __restrict__ out, int n_nodes) {
    int i = blockIdx.x * blockDim.x + threadIdx.x;
    if (i >= n_nodes) return;
    int b = i >> B2SHIFT;
    int j = i & (B2SIZE - 1);
    const float* src = rep + ((size_t)b * SLICES) * B2SIZE + j;
    float sum = ovf[i];
    #pragma unroll
    for (int s = 0; s < SLICES; ++s) sum += src[(size_t)s * B2SIZE];
    out[i] = sum;
}

extern "C" void kernel_launch(void* const* d_in, const int* in_sizes, int n_in,
                              void* d_out, int out_size, void* d_ws, size_t ws_size,
                              hipStream_t stream) {
    const int*   Z    = (const int*)d_in[0];
    const int*   eidx = (const int*)d_in[1];
    const float* len  = (const float*)d_in[2];
    float*       out  = (float*)d_out;

    const int n_nodes = in_sizes[0];
    const int n_edges = in_sizes[2];
    const int* send = eidx;
    const int* recv = eidx + n_edges;

    const int NB2 = (n_nodes + B2SIZE - 1) >> B2SHIFT;   // 98 for n=100000

    // ws layout (words): [cn n][cursor 128][ovf n][P2 2n][rep NB2*SLICES*1024][buckets 2*NB2*cap]
    char* ws = (char*)d_ws;
    int*      cn     = (int*)ws;
    unsigned* cursor = (unsigned*)(ws + (size_t)n_nodes * 4);
    float*    ovf    = (float*)(ws + (size_t)(n_nodes + MAXB) * 4);
    float2*   P2     = (float2*)(ws + (size_t)(2 * n_nodes + MAXB) * 4);
    float*    rep    = (float*)(ws + (size_t)(4 * n_nodes + MAXB) * 4);
    size_t rep_words = (size_t)NB2 * SLICES * B2SIZE;
    uint2*    buckets= (uint2*)((char*)rep + rep_words * 4);

    size_t fixed_words = (size_t)(4 * n_nodes + MAXB) + rep_words;
    size_t total_words = ws_size / 4;
    size_t bucket_words = total_words > fixed_words ? total_words - fixed_words : 0;
    long cap = (long)(bucket_words / (2 * (size_t)NB2));
    if (cap > n_edges) cap = n_edges;
    if (cap < 0) cap = 0;

    const int B = 256;
    int node_blocks = (n_nodes + B - 1) / B;
    int edge_vec    = (n_edges + 3) / 4;
    int edge_blocks = (edge_vec + B - 1) / B;
    int scat_blocks = (n_edges + TILE - 1) / TILE;
    int zero_words  = 2 * n_nodes + MAXB;   // cn + cursor + ovf

    gnb_zero<<<256, B, 0, stream>>>((int*)ws, zero_words);
    gnb_degree_cn<<<edge_blocks, B, 0, stream>>>(recv, Z, cn, n_edges);
    gnb_params<<<node_blocks, B, 0, stream>>>(Z, cn, P2, n_nodes);
    gnb_scatter<<<scat_blocks, B, 0, stream>>>(send, recv, len, P2, buckets, cursor,
                                               ovf, n_edges, (int)cap, NB2);
    gnb_gather<<<NB2 * SLICES, B, 0, stream>>>(buckets, cursor, rep, (int)cap);
    gnb_reduce<<<node_blocks, B, 0, stream>>>(rep, ovf, out, n_nodes);
}

// Round 5
// 249.381 us; speedup vs baseline: 2.6564x; 1.0111x over previous
//
#include <hip/hip_runtime.h>

// GNB dispersion — Round 5: single edge pass, degree derived from bucket records.
//   zero -> scatter_raw (route ALL edges to receiver bins, no gathers)
//        -> count (LDS histogram per bin => cn replicas)   [replaces 120us degree pass]
//        -> ovf_count -> params -> energy (LDS-staged bin P2 + P2[s] gather)
//        -> ovf_energy -> reduce
// Record: uint2{ x = s | (r&1023)<<17, y = len bits }; bucket id encodes r>>10.
// Assumes n_nodes <= 131072 (17-bit ids), NB2 <= 128.
// ws (words): [cursor 128][ocur 8][cn_extra n][ovf n][P2 2n]
//             [cnrep 98*CS*1024][rep 98*ES*1024][ovrec uint4 ocap][buckets uint2 98*cap]

#define B2SHIFT 10
#define B2SIZE  1024
#define TILE    4096
#define CSLICES 8
#define ESLICES 16
#define MAXB    128

__device__ __constant__ float2 GNB_RC6[87] = {
    {0.f, 0.f},
    {3.6516f, 95.99f},   {2.1843f, 40.67f},   {1.2711f, 70.21f},
    {3.3497f, 114.51f},  {2.7079f, 152.36f},  {1.8219f, 184.28f},
    {2.4667f, 482.54f},  {2.365f, 405.57f},   {1.5062f, 218.45f},
    {1.8233f, 174.81f},  {1.3974f, 181.7f},   {3.3515f, 263.02f},
    {3.0102f, 228.1f},   {3.1629f, 359.43f},  {3.2554f, 3222.12f},
    {2.9539f, 2144.49f}, {3.0368f, 2072.46f}, {2.6598f, 1357.42f},
    {4.0877f, 1406.65f}, {4.1275f, 1058.36f}, {9.7282f, 11498.73f},
    {8.5322f, 3361.33f}, {7.2344f, 2095.91f}, {5.3605f, 1049.31f},
    {3.718f, 966.27f},   {3.6408f, 1571.36f}, {3.4961f, 1183.59f},
    {3.5108f, 787.76f},  {3.0537f, 563.93f},  {3.0261f, 592.91f},
    {3.1735f, 430.82f},  {3.1773f, 812.57f},  {3.8357f, 4533.53f},
    {3.1109f, 3440.92f}, {3.2122f, 3859.82f}, {2.8263f, 2729.6f},
    {2.412f, 1864.19f},  {1.894f, 1175.73f},  {11.2061f, 32141.18f},
    {6.821f, 27655.14f}, {7.2367f, 2864.2f},  {3.901f, 3563.45f},
    {4.0857f, 3266.43f}, {4.045f, 3967.23f},  {3.4813f, 2233.82f},
    {3.0487f, 1393.49f}, {2.7795f, 1315.09f}, {2.8673f, 1311.47f},
    {3.3339f, 1460.56f}, {3.0086f, 1662.99f}, {3.9919f, 8089.97f},
    {3.4209f, 6887.05f}, {3.5649f, 8799.32f}, {3.0288f, 6136.5f},
    {2.262f, 3757.31f},  {1.3837f, 2561.18f}, {12.171f, 66580.83f},
    {0.f,0.f},{0.f,0.f},{0.f,0.f},{0.f,0.f},{0.f,0.f},{0.f,0.f},{0.f,0.f},
    {0.f,0.f},{0.f,0.f},{0.f,0.f},{0.f,0.f},{0.f,0.f},{0.f,0.f},{0.f,0.f},
    {6.0791f, 27593.76f}, {5.7661f, 15364.65f}, {3.6366f, 2734.5f},
    {4.241f, 4801.82f},   {4.1348f, 5685.94f},  {3.4213f, 2786.0f},
    {3.2486f, 2699.79f},  {2.9588f, 2282.6f},   {2.9381f, 2476.79f},
    {2.7711f, 2988.7f},   {2.5816f, 2506.63f},  {3.785f, 8916.84f},
    {3.5381f, 8694.22f},  {3.6985f, 11821.61f}, {3.0551f, 8410.64f},
};

__global__ void gnb_zero(int* __restrict__ p, int n) {
    int stride = gridDim.x * blockDim.x;
    for (int i = blockIdx.x * blockDim.x + threadIdx.x; i < n; i += stride)
        p[i] = 0;
}

// Route every edge into its receiver bin. No gathers, no math.
__global__ void __launch_bounds__(256)
gnb_scatter_raw(const int* __restrict__ send, const int* __restrict__ recv,
                const float* __restrict__ len,
                uint2* __restrict__ buckets, unsigned* __restrict__ cursor,
                uint4* __restrict__ ovrec, unsigned* __restrict__ ocur,
                int n_edges, int cap, unsigned ocap, int NB2) {
    __shared__ unsigned cnt[MAXB];
    __shared__ unsigned gbase[MAXB];
    const int tid = threadIdx.x;
    const int e0  = blockIdx.x * TILE;

    for (int b = tid; b < MAXB; b += 256) cnt[b] = 0;
    __syncthreads();

    unsigned keyA[16];   // r | rank<<17 ; 0xFFFFFFFF = invalid (tail)
    unsigned keyS[16];
    unsigned keyL[16];

    #pragma unroll
    for (int k = 0; k < 4; ++k) {
        int base = e0 + (k * 256 + tid) * 4;
        int s4[4], r4[4]; unsigned l4[4];
        int nv = 0;
        if (base + 3 < n_edges) {
            int4  sv = *(const int4*)(send + base);
            int4  rv = *(const int4*)(recv + base);
            uint4 lv = *(const uint4*)(len + base);
            s4[0]=sv.x; s4[1]=sv.y; s4[2]=sv.z; s4[3]=sv.w;
            r4[0]=rv.x; r4[1]=rv.y; r4[2]=rv.z; r4[3]=rv.w;
            l4[0]=lv.x; l4[1]=lv.y; l4[2]=lv.z; l4[3]=lv.w;
            nv = 4;
        } else {
            for (int e = base; e < n_edges; ++e) {
                s4[nv] = send[e]; r4[nv] = recv[e];
                l4[nv] = ((const unsigned*)len)[e]; ++nv;
            }
        }
        #pragma unroll
        for (int j = 0; j < 4; ++j) {
            int idx = k * 4 + j;
            keyA[idx] = 0xFFFFFFFFu;
            if (j < nv) {
                unsigned r = (unsigned)r4[j];
                unsigned rank = atomicAdd(&cnt[r >> B2SHIFT], 1u);
                keyA[idx] = r | (rank << 17);
                keyS[idx] = (unsigned)s4[j];
                keyL[idx] = l4[j];
            }
        }
    }
    __syncthreads();
    if (tid < NB2) gbase[tid] = atomicAdd(&cursor[tid], cnt[tid]);
    __syncthreads();

    #pragma unroll
    for (int i = 0; i < 16; ++i) {
        unsigned ka = keyA[i];
        if (ka == 0xFFFFFFFFu) continue;
        unsigned r    = ka & 0x1FFFFu;
        unsigned rank = ka >> 17;
        unsigned b    = r >> B2SHIFT;
        unsigned slot = gbase[b] + rank;
        if (slot < (unsigned)cap) {
            buckets[(size_t)b * cap + slot] =
                make_uint2(keyS[i] | ((r & (B2SIZE - 1)) << 17), keyL[i]);
        } else {
            unsigned o = atomicAdd(ocur, 1u);
            if (o < ocap) ovrec[o] = make_uint4(r, keyS[i], keyL[i], 0u);
        }
    }
}

// Per (bin,slice): histogram record receivers -> cn replica (coalesced store).
__global__ void __launch_bounds__(256)
gnb_count(const uint2* __restrict__ buckets, const unsigned* __restrict__ cursor,
          int* __restrict__ cnrep, int cap) {
    __shared__ int acc[B2SIZE];
    const int b   = blockIdx.x / CSLICES;
    const int sl  = blockIdx.x % CSLICES;
    const int tid = threadIdx.x;

    for (int i = tid; i < B2SIZE; i += 256) acc[i] = 0;
    __syncthreads();

    unsigned count = cursor[b];
    if (count > (unsigned)cap) count = (unsigned)cap;
    unsigned seg = (count + CSLICES - 1) / CSLICES;
    unsigned st  = (unsigned)sl * seg;
    unsigned en  = st + seg; if (en > count) en = count;

    const uint2* src = buckets + (size_t)b * cap;
    for (unsigned i = st + tid; i < en; i += 256)
        atomicAdd(&acc[(src[i].x >> 17) & (B2SIZE - 1)], 1);
    __syncthreads();

    int* dst = cnrep + (size_t)blockIdx.x * B2SIZE;
    for (int i = tid; i < B2SIZE; i += 256) dst[i] = acc[i];
}

// Overflow records also contribute to cn (only C/N receivers matter).
__global__ void gnb_ovf_count(const uint4* __restrict__ ovrec, const unsigned* __restrict__ ocur,
                              const int* __restrict__ Z, int* __restrict__ cn_extra,
                              unsigned ocap) {
    unsigned n = *ocur; if (n > ocap) n = ocap;
    int stride = gridDim.x * blockDim.x;
    for (unsigned i = blockIdx.x * blockDim.x + threadIdx.x; i < n; i += stride) {
        unsigned r = ovrec[i].x;
        int z = Z[r];
        if (z == 6 || z == 7) atomicAdd(&cn_extra[r], 1);
    }
}

__global__ void gnb_params(const int* __restrict__ Z, const int* __restrict__ cnrep,
                           const int* __restrict__ cn_extra, float2* __restrict__ P2,
                           int n_nodes) {
    int i = blockIdx.x * blockDim.x + threadIdx.x;
    if (i >= n_nodes) return;
    int z = Z[i];
    float Rp, C6;
    if (z == 6 || z == 7) {
        int b = i >> B2SHIFT, j = i & (B2SIZE - 1);
        int cn = cn_extra[i];
        #pragma unroll
        for (int s = 0; s < CSLICES; ++s)
            cn += cnrep[((size_t)b * CSLICES + s) * B2SIZE + j];
        if (z == 6) {
            if (cn <= 3) { Rp = 2.2348f; C6 = 429.69f; }
            else         { Rp = 1.8219f; C6 = 184.28f; }
        } else {
            if (cn <= 2) { Rp = 2.6454f; C6 = 720.18f; }
            else         { Rp = 2.4667f; C6 = 482.54f; }
        }
    } else {
        float2 rc = GNB_RC6[z];
        Rp = rc.x; C6 = rc.y;
    }
    P2[i] = make_float2(sqrtf(C6), sqrtf(sqrtf(Rp)));
}

__device__ __forceinline__ float gnb_energy_eval(float2 ps, float2 pr, float rlen) {
    float env;
    if (rlen < 8.0f) {
        env = 1.0f;
    } else {
        float x = (rlen - 8.0f) * 0.5f;          // caller guarantees x < 1
        float x2 = x * x;
        float x6 = x2 * x2 * x2;
        env = 1.0f - 28.0f * x6 + 48.0f * x6 * x - 21.0f * x6 * x2;
    }
    float sR  = ps.y * pr.y;                     // sqrt(R_ij)
    float C6  = ps.x * pr.x;                     // sqrt(C6_s*C6_r)
    float Rij = sR * sR;
    float R3  = Rij * Rij * Rij;
    float R6  = R3 * R3;
    float r0  = 0.4f * sR + 4.0f;
    float t   = r0 / rlen;
    float t2 = t * t, t4 = t2 * t2, t8 = t4 * t4;
    float t14 = t8 * t4 * t2;
    float fd = 1.0f / (1.0f + 6.0f * t14);
    float rl2 = rlen * rlen;
    float r6 = rl2 * rl2 * rl2;
    return -0.5f * C6 / (R6 + r6) * fd * env;
}

// Per (bin,slice): bin's P2 staged in LDS; one P2[s] gather per record.
__global__ void __launch_bounds__(256)
gnb_energy(const uint2* __restrict__ buckets, const unsigned* __restrict__ cursor,
           const float2* __restrict__ P2, float* __restrict__ rep,
           int cap, int n_nodes) {
    __shared__ float  acc[B2SIZE];
    __shared__ float2 p2loc[B2SIZE];
    const int b   = blockIdx.x / ESLICES;
    const int sl  = blockIdx.x % ESLICES;
    const int tid = threadIdx.x;

    for (int i = tid; i < B2SIZE; i += 256) {
        acc[i] = 0.0f;
        int node = (b << B2SHIFT) + i;
        p2loc[i] = (node < n_nodes) ? P2[node] : make_float2(0.f, 0.f);
    }
    __syncthreads();

    unsigned count = cursor[b];
    if (count > (unsigned)cap) count = (unsigned)cap;
    unsigned seg = (count + ESLICES - 1) / ESLICES;
    unsigned st  = (unsigned)sl * seg;
    unsigned en  = st + seg; if (en > count) en = count;

    const uint2* src = buckets + (size_t)b * cap;
    for (unsigned i = st + tid; i < en; i += 256) {
        uint2 rec = src[i];
        float rlen = __uint_as_float(rec.y);
        if (rlen >= 10.0f) continue;             // env == 0
        unsigned s    = rec.x & 0x1FFFFu;
        unsigned rlow = (rec.x >> 17) & (B2SIZE - 1);
        float e = gnb_energy_eval(P2[s], p2loc[rlow], rlen);
        atomicAdd(&acc[rlow], e);
    }
    __syncthreads();

    float* dst = rep + (size_t)blockIdx.x * B2SIZE;
    for (int i = tid; i < B2SIZE; i += 256) dst[i] = acc[i];
}

__global__ void gnb_ovf_energy(const uint4* __restrict__ ovrec, const unsigned* __restrict__ ocur,
                               const float2* __restrict__ P2, float* __restrict__ ovf,
                               unsigned ocap) {
    unsigned n = *ocur; if (n > ocap) n = ocap;
    int stride = gridDim.x * blockDim.x;
    for (unsigned i = blockIdx.x * blockDim.x + threadIdx.x; i < n; i += stride) {
        uint4 rec = ovrec[i];
        float rlen = __uint_as_float(rec.z);
        if (rlen >= 10.0f) continue;
        float e = gnb_energy_eval(P2[rec.y], P2[rec.x], rlen);
        atomicAdd(&ovf[rec.x], e);
    }
}

__global__ void gnb_reduce(const float* __restrict__ rep, const float* __restrict__ ovf,
                           float* __restrict__ out, int n_nodes) {
    int i = blockIdx.x * blockDim.x + threadIdx.x;
    if (i >= n_nodes) return;
    int b = i >> B2SHIFT;
    int j = i & (B2SIZE - 1);
    const float* src = rep + ((size_t)b * ESLICES) * B2SIZE + j;
    float sum = ovf[i];
    #pragma unroll
    for (int s = 0; s < ESLICES; ++s) sum += src[(size_t)s * B2SIZE];
    out[i] = sum;
}

extern "C" void kernel_launch(void* const* d_in, const int* in_sizes, int n_in,
                              void* d_out, int out_size, void* d_ws, size_t ws_size,
                              hipStream_t stream) {
    const int*   Z    = (const int*)d_in[0];
    const int*   eidx = (const int*)d_in[1];
    const float* len  = (const float*)d_in[2];
    float*       out  = (float*)d_out;

    const int n_nodes = in_sizes[0];
    const int n_edges = in_sizes[2];
    const int* send = eidx;
    const int* recv = eidx + n_edges;

    const int NB2 = (n_nodes + B2SIZE - 1) >> B2SHIFT;   // 98 for n=100000

    // ws layout (words)
    char* ws = (char*)d_ws;
    unsigned* cursor   = (unsigned*)ws;                                  // 128
    unsigned* ocur     = (unsigned*)(ws + MAXB * 4);                     // 8
    int*      cn_extra = (int*)(ws + (MAXB + 8) * 4);                    // n
    float*    ovf      = (float*)(ws + ((size_t)n_nodes + MAXB + 8) * 4);        // n
    float2*   P2       = (float2*)(ws + ((size_t)2 * n_nodes + MAXB + 8) * 4);   // 2n
    int*      cnrep    = (int*)(ws + ((size_t)4 * n_nodes + MAXB + 8) * 4);
    size_t cnrep_w     = (size_t)NB2 * CSLICES * B2SIZE;
    float*    rep      = (float*)((char*)cnrep + cnrep_w * 4);
    size_t rep_w       = (size_t)NB2 * ESLICES * B2SIZE;
    char*     tail     = (char*)rep + rep_w * 4;

    size_t fixed_words = (size_t)4 * n_nodes + MAXB + 8 + cnrep_w + rep_w;
    size_t total_words = ws_size / 4;
    size_t avail = total_words > fixed_words ? total_words - fixed_words : 0;
    size_t ovw = avail / 32;                      // ~3% to overflow queue
    unsigned ocap = (unsigned)(ovw / 4);
    long cap = (long)((avail - ovw) / (2 * (size_t)NB2));
    if (cap > n_edges) cap = n_edges;
    if (cap < 0) cap = 0;
    uint4* ovrec   = (uint4*)tail;
    uint2* buckets = (uint2*)(tail + (size_t)ocap * 16);

    const int B = 256;
    int node_blocks = (n_nodes + B - 1) / B;
    int scat_blocks = (n_edges + TILE - 1) / TILE;
    int zero_words  = 2 * n_nodes + MAXB + 8;     // cursor + ocur + cn_extra + ovf

    gnb_zero<<<256, B, 0, stream>>>((int*)ws, zero_words);
    gnb_scatter_raw<<<scat_blocks, B, 0, stream>>>(send, recv, len, buckets, cursor,
                                                   ovrec, ocur, n_edges, (int)cap, ocap, NB2);
    gnb_count<<<NB2 * CSLICES, B, 0, stream>>>(buckets, cursor, cnrep, (int)cap);
    gnb_ovf_count<<<8, B, 0, stream>>>(ovrec, ocur, Z, cn_extra, ocap);
    gnb_params<<<node_blocks, B, 0, stream>>>(Z, cnrep, cn_extra, P2, n_nodes);
    gnb_energy<<<NB2 * ESLICES, B, 0, stream>>>(buckets, cursor, P2, rep, (int)cap, n_nodes);
    gnb_ovf_energy<<<8, B, 0, stream>>>(ovrec, ocur, P2, ovf, ocap);
    gnb_reduce<<<node_blocks, B, 0, stream>>>(rep, ovf, out, n_nodes);
}

// Round 6
// 212.639 us; speedup vs baseline: 3.1154x; 1.1728x over previous
//
#include <hip/hip_runtime.h>

// GNB dispersion — Round 6: LDS-compacted scatter w/ coalesced bucket writes,
// degree fused into scatter via L1-resident isCN bitmask (no count pass).
//   init (zero + isCN bitmask) -> scatter (sorted-tile routing + filtered cn atomics)
//   -> params -> energy (LDS bin accumulate, replica store) -> ovf_energy -> reduce
// Record: uint2{ x = s | (r&1023)<<17, y = len bits }; bucket id = r>>10.
// Assumes n_nodes <= 131072 (17-bit ids), NB2 <= 128.
// ws (words): [cursor 128][ocur 8][cn n][ovf n][P2 2n][isCN nw]
//             [rep NB2*ES*1024][ovrec uint4 ocap][buckets uint2 NB2*cap]

#define B2SHIFT 10
#define B2SIZE  1024
#define TILE    4096
#define ESLICES 16
#define MAXB    128

__device__ __constant__ float2 GNB_RC6[87] = {
    {0.f, 0.f},
    {3.6516f, 95.99f},   {2.1843f, 40.67f},   {1.2711f, 70.21f},
    {3.3497f, 114.51f},  {2.7079f, 152.36f},  {1.8219f, 184.28f},
    {2.4667f, 482.54f},  {2.365f, 405.57f},   {1.5062f, 218.45f},
    {1.8233f, 174.81f},  {1.3974f, 181.7f},   {3.3515f, 263.02f},
    {3.0102f, 228.1f},   {3.1629f, 359.43f},  {3.2554f, 3222.12f},
    {2.9539f, 2144.49f}, {3.0368f, 2072.46f}, {2.6598f, 1357.42f},
    {4.0877f, 1406.65f}, {4.1275f, 1058.36f}, {9.7282f, 11498.73f},
    {8.5322f, 3361.33f}, {7.2344f, 2095.91f}, {5.3605f, 1049.31f},
    {3.718f, 966.27f},   {3.6408f, 1571.36f}, {3.4961f, 1183.59f},
    {3.5108f, 787.76f},  {3.0537f, 563.93f},  {3.0261f, 592.91f},
    {3.1735f, 430.82f},  {3.1773f, 812.57f},  {3.8357f, 4533.53f},
    {3.1109f, 3440.92f}, {3.2122f, 3859.82f}, {2.8263f, 2729.6f},
    {2.412f, 1864.19f},  {1.894f, 1175.73f},  {11.2061f, 32141.18f},
    {6.821f, 27655.14f}, {7.2367f, 2864.2f},  {3.901f, 3563.45f},
    {4.0857f, 3266.43f}, {4.045f, 3967.23f},  {3.4813f, 2233.82f},
    {3.0487f, 1393.49f}, {2.7795f, 1315.09f}, {2.8673f, 1311.47f},
    {3.3339f, 1460.56f}, {3.0086f, 1662.99f}, {3.9919f, 8089.97f},
    {3.4209f, 6887.05f}, {3.5649f, 8799.32f}, {3.0288f, 6136.5f},
    {2.262f, 3757.31f},  {1.3837f, 2561.18f}, {12.171f, 66580.83f},
    {0.f,0.f},{0.f,0.f},{0.f,0.f},{0.f,0.f},{0.f,0.f},{0.f,0.f},{0.f,0.f},
    {0.f,0.f},{0.f,0.f},{0.f,0.f},{0.f,0.f},{0.f,0.f},{0.f,0.f},{0.f,0.f},
    {6.0791f, 27593.76f}, {5.7661f, 15364.65f}, {3.6366f, 2734.5f},
    {4.241f, 4801.82f},   {4.1348f, 5685.94f},  {3.4213f, 2786.0f},
    {3.2486f, 2699.79f},  {2.9588f, 2282.6f},   {2.9381f, 2476.79f},
    {2.7711f, 2988.7f},   {2.5816f, 2506.63f},  {3.785f, 8916.84f},
    {3.5381f, 8694.22f},  {3.6985f, 11821.61f}, {3.0551f, 8410.64f},
};

// Zero scratch + build bit-packed isCN mask (12.5KB -> L1-resident in scatter).
__global__ void gnb_init(const int* __restrict__ Z, unsigned* __restrict__ isCN,
                         int nw, int n_nodes, int* __restrict__ zp, int zwords) {
    int stride = gridDim.x * blockDim.x;
    int t0 = blockIdx.x * blockDim.x + threadIdx.x;
    for (int i = t0; i < zwords; i += stride) zp[i] = 0;
    for (int w = t0; w < nw; w += stride) {
        unsigned m = 0;
        int base = w << 5;
        int lim = n_nodes - base; if (lim > 32) lim = 32;
        for (int k = 0; k < lim; ++k) {
            int z = Z[base + k];
            if (z == 6 || z == 7) m |= (1u << k);
        }
        isCN[w] = m;
    }
}

// Tile scatter: pass1 histogram + filtered degree atomics; prefix-scan;
// pass2 place records bucket-sorted in LDS; phaseC coalesced global copy.
__global__ void __launch_bounds__(256)
gnb_scatter(const int* __restrict__ send, const int* __restrict__ recv,
            const float* __restrict__ len, const unsigned* __restrict__ isCN,
            int* __restrict__ cn,
            uint2* __restrict__ buckets, unsigned* __restrict__ cursor,
            uint4* __restrict__ ovrec, unsigned* __restrict__ ocur,
            int n_edges, int cap, unsigned ocap, int NB2) {
    __shared__ unsigned cnt[MAXB];
    __shared__ unsigned pos[MAXB];
    __shared__ unsigned startp[MAXB + 1];
    __shared__ unsigned gbase[MAXB];
    __shared__ uint2 srec[TILE];             // 32 KB, bucket-sorted records
    __shared__ unsigned char bmap[TILE];     // 4 KB, slot -> bucket
    const int tid = threadIdx.x;
    const int e0  = blockIdx.x * TILE;

    for (int b = tid; b < MAXB; b += 256) { cnt[b] = 0; pos[b] = 0; }
    __syncthreads();

    // pass 1: bucket histogram + fused filtered degree (~2.3% of lanes atomic)
    #pragma unroll
    for (int k = 0; k < 4; ++k) {
        int base = e0 + (k * 256 + tid) * 4;
        if (base + 3 < n_edges) {
            int4 rv = *(const int4*)(recv + base);
            int rr[4] = {rv.x, rv.y, rv.z, rv.w};
            #pragma unroll
            for (int j = 0; j < 4; ++j) {
                unsigned r = (unsigned)rr[j];
                atomicAdd(&cnt[r >> B2SHIFT], 1u);
                if ((isCN[r >> 5] >> (r & 31)) & 1u) atomicAdd(&cn[r], 1);
            }
        } else {
            int lim = n_edges - base; if (lim > 4) lim = 4;
            for (int j = 0; j < lim; ++j) {
                unsigned r = (unsigned)recv[base + j];
                atomicAdd(&cnt[r >> B2SHIFT], 1u);
                if ((isCN[r >> 5] >> (r & 31)) & 1u) atomicAdd(&cn[r], 1);
            }
        }
    }
    __syncthreads();

    if (tid == 0) {                           // 98-entry serial scan: trivial
        unsigned acc = 0;
        for (int b = 0; b < NB2; ++b) { startp[b] = acc; acc += cnt[b]; }
        startp[NB2] = acc;
    }
    __syncthreads();
    if (tid < NB2) gbase[tid] = atomicAdd(&cursor[tid], cnt[tid]);
    __syncthreads();

    // pass 2: reload tile (L1/L2-warm), place records sorted-by-bucket in LDS
    #pragma unroll
    for (int k = 0; k < 4; ++k) {
        int base = e0 + (k * 256 + tid) * 4;
        if (base + 3 < n_edges) {
            int4  sv = *(const int4*)(send + base);
            int4  rv = *(const int4*)(recv + base);
            uint4 lv = *(const uint4*)(len + base);
            int ss[4] = {sv.x, sv.y, sv.z, sv.w};
            int rr[4] = {rv.x, rv.y, rv.z, rv.w};
            unsigned ll[4] = {lv.x, lv.y, lv.z, lv.w};
            #pragma unroll
            for (int j = 0; j < 4; ++j) {
                unsigned r = (unsigned)rr[j];
                unsigned b = r >> B2SHIFT;
                unsigned slot = startp[b] + atomicAdd(&pos[b], 1u);
                srec[slot] = make_uint2((unsigned)ss[j] | ((r & (B2SIZE - 1)) << 17), ll[j]);
                bmap[slot] = (unsigned char)b;
            }
        } else {
            int lim = n_edges - base; if (lim > 4) lim = 4;
            for (int j = 0; j < lim; ++j) {
                unsigned r = (unsigned)recv[base + j];
                unsigned b = r >> B2SHIFT;
                unsigned slot = startp[b] + atomicAdd(&pos[b], 1u);
                srec[slot] = make_uint2((unsigned)send[base + j] | ((r & (B2SIZE - 1)) << 17),
                                        ((const unsigned*)len)[base + j]);
                bmap[slot] = (unsigned char)b;
            }
        }
    }
    __syncthreads();

    // phase C: coalesced copy — consecutive slots hit contiguous bucket runs
    unsigned total = startp[NB2];
    for (unsigned i = tid; i < total; i += 256) {
        unsigned b = bmap[i];
        unsigned g = gbase[b] + (i - startp[b]);
        uint2 rec = srec[i];
        if (g < (unsigned)cap) {
            buckets[(size_t)b * cap + g] = rec;
        } else {
            unsigned o = atomicAdd(ocur, 1u);
            unsigned r = ((unsigned)b << B2SHIFT) | ((rec.x >> 17) & (B2SIZE - 1));
            if (o < ocap) ovrec[o] = make_uint4(r, rec.x & 0x1FFFFu, rec.y, 0u);
        }
    }
}

__global__ void gnb_params(const int* __restrict__ Z, const int* __restrict__ cn,
                           float2* __restrict__ P2, int n_nodes) {
    int i = blockIdx.x * blockDim.x + threadIdx.x;
    if (i >= n_nodes) return;
    int z = Z[i];
    float Rp, C6;
    if (z == 6) {
        if (cn[i] <= 3) { Rp = 2.2348f; C6 = 429.69f; }
        else            { Rp = 1.8219f; C6 = 184.28f; }
    } else if (z == 7) {
        if (cn[i] <= 2) { Rp = 2.6454f; C6 = 720.18f; }
        else            { Rp = 2.4667f; C6 = 482.54f; }
    } else {
        float2 rc = GNB_RC6[z];
        Rp = rc.x; C6 = rc.y;
    }
    P2[i] = make_float2(sqrtf(C6), sqrtf(sqrtf(Rp)));
}

__device__ __forceinline__ float gnb_energy_eval(float2 ps, float2 pr, float rlen) {
    float env;
    if (rlen < 8.0f) {
        env = 1.0f;
    } else {
        float x = (rlen - 8.0f) * 0.5f;          // caller guarantees x < 1
        float x2 = x * x;
        float x6 = x2 * x2 * x2;
        env = 1.0f - 28.0f * x6 + 48.0f * x6 * x - 21.0f * x6 * x2;
    }
    float sR  = ps.y * pr.y;                     // sqrt(R_ij)
    float C6  = ps.x * pr.x;                     // sqrt(C6_s*C6_r)
    float Rij = sR * sR;
    float R3  = Rij * Rij * Rij;
    float R6  = R3 * R3;
    float r0  = 0.4f * sR + 4.0f;
    float t   = r0 / rlen;
    float t2 = t * t, t4 = t2 * t2, t8 = t4 * t4;
    float t14 = t8 * t4 * t2;
    float fd = 1.0f / (1.0f + 6.0f * t14);
    float rl2 = rlen * rlen;
    float r6 = rl2 * rl2 * rl2;
    return -0.5f * C6 / (R6 + r6) * fd * env;
}

// Per (bin,slice): bin's P2 staged in LDS; one P2[s] gather per record.
__global__ void __launch_bounds__(256)
gnb_energy(const uint2* __restrict__ buckets, const unsigned* __restrict__ cursor,
           const float2* __restrict__ P2, float* __restrict__ rep,
           int cap, int n_nodes) {
    __shared__ float  acc[B2SIZE];
    __shared__ float2 p2loc[B2SIZE];
    const int b   = blockIdx.x / ESLICES;
    const int sl  = blockIdx.x % ESLICES;
    const int tid = threadIdx.x;

    for (int i = tid; i < B2SIZE; i += 256) {
        acc[i] = 0.0f;
        int node = (b << B2SHIFT) + i;
        p2loc[i] = (node < n_nodes) ? P2[node] : make_float2(0.f, 0.f);
    }
    __syncthreads();

    unsigned count = cursor[b];
    if (count > (unsigned)cap) count = (unsigned)cap;
    unsigned seg = (count + ESLICES - 1) / ESLICES;
    unsigned st  = (unsigned)sl * seg;
    unsigned en  = st + seg; if (en > count) en = count;

    const uint2* src = buckets + (size_t)b * cap;
    for (unsigned i = st + tid; i < en; i += 256) {
        uint2 rec = src[i];
        float rlen = __uint_as_float(rec.y);
        if (rlen >= 10.0f) continue;             // env == 0
        unsigned s    = rec.x & 0x1FFFFu;
        unsigned rlow = (rec.x >> 17) & (B2SIZE - 1);
        float e = gnb_energy_eval(P2[s], p2loc[rlow], rlen);
        atomicAdd(&acc[rlow], e);
    }
    __syncthreads();

    float* dst = rep + (size_t)blockIdx.x * B2SIZE;
    for (int i = tid; i < B2SIZE; i += 256) dst[i] = acc[i];
}

__global__ void gnb_ovf_energy(const uint4* __restrict__ ovrec, const unsigned* __restrict__ ocur,
                               const float2* __restrict__ P2, float* __restrict__ ovf,
                               unsigned ocap) {
    unsigned n = *ocur; if (n > ocap) n = ocap;
    int stride = gridDim.x * blockDim.x;
    for (unsigned i = blockIdx.x * blockDim.x + threadIdx.x; i < n; i += stride) {
        uint4 rec = ovrec[i];
        float rlen = __uint_as_float(rec.z);
        if (rlen >= 10.0f) continue;
        float e = gnb_energy_eval(P2[rec.y], P2[rec.x], rlen);
        atomicAdd(&ovf[rec.x], e);
    }
}

__global__ void gnb_reduce(const float* __restrict__ rep, const float* __restrict__ ovf,
                           float* __restrict__ out, int n_nodes) {
    int i = blockIdx.x * blockDim.x + threadIdx.x;
    if (i >= n_nodes) return;
    int b = i >> B2SHIFT;
    int j = i & (B2SIZE - 1);
    const float* src = rep + ((size_t)b * ESLICES) * B2SIZE + j;
    float sum = ovf[i];
    #pragma unroll
    for (int s = 0; s < ESLICES; ++s) sum += src[(size_t)s * B2SIZE];
    out[i] = sum;
}

extern "C" void kernel_launch(void* const* d_in, const int* in_sizes, int n_in,
                              void* d_out, int out_size, void* d_ws, size_t ws_size,
                              hipStream_t stream) {
    const int*   Z    = (const int*)d_in[0];
    const int*   eidx = (const int*)d_in[1];
    const float* len  = (const float*)d_in[2];
    float*       out  = (float*)d_out;

    const int n_nodes = in_sizes[0];
    const int n_edges = in_sizes[2];
    const int* send = eidx;
    const int* recv = eidx + n_edges;

    const int NB2 = (n_nodes + B2SIZE - 1) >> B2SHIFT;   // 98 for n=100000
    const int nw  = (n_nodes + 31) >> 5;                 // isCN words
    const int nwp = (nw + 7) & ~7;

    // ws layout (words)
    char* ws = (char*)d_ws;
    unsigned* cursor = (unsigned*)ws;                                        // 128
    unsigned* ocur   = (unsigned*)(ws + MAXB * 4);                           // 8
    int*      cn     = (int*)(ws + (MAXB + 8) * 4);                          // n
    float*    ovf    = (float*)(ws + ((size_t)n_nodes + MAXB + 8) * 4);      // n
    float2*   P2     = (float2*)(ws + ((size_t)2 * n_nodes + MAXB + 8) * 4); // 2n
    unsigned* isCN   = (unsigned*)(ws + ((size_t)4 * n_nodes + MAXB + 8) * 4); // nwp
    float*    rep    = (float*)((char*)isCN + (size_t)nwp * 4);
    size_t rep_w     = (size_t)NB2 * ESLICES * B2SIZE;
    char*     tail   = (char*)rep + rep_w * 4;

    size_t fixed_words = (size_t)4 * n_nodes + MAXB + 8 + nwp + rep_w;
    size_t total_words = ws_size / 4;
    size_t avail = total_words > fixed_words ? total_words - fixed_words : 0;
    size_t ovw = avail / 32;                      // ~3% to overflow queue
    unsigned ocap = (unsigned)(ovw / 4);
    long cap = (long)((avail - ovw) / (2 * (size_t)NB2));
    if (cap > n_edges) cap = n_edges;
    if (cap < 0) cap = 0;
    uint4* ovrec   = (uint4*)tail;
    uint2* buckets = (uint2*)(tail + (size_t)ocap * 16);

    const int B = 256;
    int node_blocks = (n_nodes + B - 1) / B;
    int scat_blocks = (n_edges + TILE - 1) / TILE;
    int zero_words  = 2 * n_nodes + MAXB + 8;     // cursor + ocur + cn + ovf

    gnb_init<<<256, B, 0, stream>>>(Z, isCN, nw, n_nodes, (int*)ws, zero_words);
    gnb_scatter<<<scat_blocks, B, 0, stream>>>(send, recv, len, isCN, cn, buckets,
                                               cursor, ovrec, ocur, n_edges,
                                               (int)cap, ocap, NB2);
    gnb_params<<<node_blocks, B, 0, stream>>>(Z, cn, P2, n_nodes);
    gnb_energy<<<NB2 * ESLICES, B, 0, stream>>>(buckets, cursor, P2, rep, (int)cap, n_nodes);
    gnb_ovf_energy<<<8, B, 0, stream>>>(ovrec, ocur, P2, ovf, ocap);
    gnb_reduce<<<node_blocks, B, 0, stream>>>(rep, ovf, out, n_nodes);
}

// Round 7
// 203.246 us; speedup vs baseline: 3.2594x; 1.0462x over previous
//
#include <hip/hip_runtime.h>

// GNB dispersion — Round 7: full-occupancy scatter (512thr) + r>=10 filtering at
// scatter + double-accumulator energy gather at 32 slices.
//   init (zero + isCN bitmask) -> scatter (histogram+degree / sort-in-LDS / coalesced
//   bucket stores) -> params -> energy -> ovf_energy -> reduce
// Record: uint2{ x = s | (r&1023)<<17, y = len bits }; bucket id = r>>10.
// Assumes n_nodes <= 131072 (17-bit ids), NB2 <= 128.
// ws (words): [cursor 128][ocur 8][cn n][ovf n][P2 2n][isCN nw]
//             [rep NB2*ES*1024][ovrec uint4 ocap][buckets uint2 NB2*cap]

#define B2SHIFT 10
#define B2SIZE  1024
#define TILE    4096
#define SBLK    512
#define ESLICES 32
#define MAXB    128

__device__ __constant__ float2 GNB_RC6[87] = {
    {0.f, 0.f},
    {3.6516f, 95.99f},   {2.1843f, 40.67f},   {1.2711f, 70.21f},
    {3.3497f, 114.51f},  {2.7079f, 152.36f},  {1.8219f, 184.28f},
    {2.4667f, 482.54f},  {2.365f, 405.57f},   {1.5062f, 218.45f},
    {1.8233f, 174.81f},  {1.3974f, 181.7f},   {3.3515f, 263.02f},
    {3.0102f, 228.1f},   {3.1629f, 359.43f},  {3.2554f, 3222.12f},
    {2.9539f, 2144.49f}, {3.0368f, 2072.46f}, {2.6598f, 1357.42f},
    {4.0877f, 1406.65f}, {4.1275f, 1058.36f}, {9.7282f, 11498.73f},
    {8.5322f, 3361.33f}, {7.2344f, 2095.91f}, {5.3605f, 1049.31f},
    {3.718f, 966.27f},   {3.6408f, 1571.36f}, {3.4961f, 1183.59f},
    {3.5108f, 787.76f},  {3.0537f, 563.93f},  {3.0261f, 592.91f},
    {3.1735f, 430.82f},  {3.1773f, 812.57f},  {3.8357f, 4533.53f},
    {3.1109f, 3440.92f}, {3.2122f, 3859.82f}, {2.8263f, 2729.6f},
    {2.412f, 1864.19f},  {1.894f, 1175.73f},  {11.2061f, 32141.18f},
    {6.821f, 27655.14f}, {7.2367f, 2864.2f},  {3.901f, 3563.45f},
    {4.0857f, 3266.43f}, {4.045f, 3967.23f},  {3.4813f, 2233.82f},
    {3.0487f, 1393.49f}, {2.7795f, 1315.09f}, {2.8673f, 1311.47f},
    {3.3339f, 1460.56f}, {3.0086f, 1662.99f}, {3.9919f, 8089.97f},
    {3.4209f, 6887.05f}, {3.5649f, 8799.32f}, {3.0288f, 6136.5f},
    {2.262f, 3757.31f},  {1.3837f, 2561.18f}, {12.171f, 66580.83f},
    {0.f,0.f},{0.f,0.f},{0.f,0.f},{0.f,0.f},{0.f,0.f},{0.f,0.f},{0.f,0.f},
    {0.f,0.f},{0.f,0.f},{0.f,0.f},{0.f,0.f},{0.f,0.f},{0.f,0.f},{0.f,0.f},
    {6.0791f, 27593.76f}, {5.7661f, 15364.65f}, {3.6366f, 2734.5f},
    {4.241f, 4801.82f},   {4.1348f, 5685.94f},  {3.4213f, 2786.0f},
    {3.2486f, 2699.79f},  {2.9588f, 2282.6f},   {2.9381f, 2476.79f},
    {2.7711f, 2988.7f},   {2.5816f, 2506.63f},  {3.785f, 8916.84f},
    {3.5381f, 8694.22f},  {3.6985f, 11821.61f}, {3.0551f, 8410.64f},
};

// Zero scratch + build bit-packed isCN mask (12.5KB -> L1-resident in scatter).
__global__ void gnb_init(const int* __restrict__ Z, unsigned* __restrict__ isCN,
                         int nw, int n_nodes, int* __restrict__ zp, int zwords) {
    int stride = gridDim.x * blockDim.x;
    int t0 = blockIdx.x * blockDim.x + threadIdx.x;
    for (int i = t0; i < zwords; i += stride) zp[i] = 0;
    for (int w = t0; w < nw; w += stride) {
        unsigned m = 0;
        int base = w << 5;
        int lim = n_nodes - base; if (lim > 32) lim = 32;
        for (int k = 0; k < lim; ++k) {
            int z = Z[base + k];
            if (z == 6 || z == 7) m |= (1u << k);
        }
        isCN[w] = m;
    }
}

// Tile scatter, 512 threads (8 waves -> 4 blocks/CU = 32 waves/CU):
//   pass1: histogram kept records (len<10) + degree for ALL edges (isCN-filtered)
//   scan + cursor bump; pass2: reload tile, place records bucket-sorted in LDS;
//   phaseC: coalesced copy of bucket runs to global.
__global__ void __launch_bounds__(SBLK)
gnb_scatter(const int* __restrict__ send, const int* __restrict__ recv,
            const float* __restrict__ len, const unsigned* __restrict__ isCN,
            int* __restrict__ cn,
            uint2* __restrict__ buckets, unsigned* __restrict__ cursor,
            uint4* __restrict__ ovrec, unsigned* __restrict__ ocur,
            int n_edges, int cap, unsigned ocap, int NB2) {
    __shared__ unsigned cnt[MAXB];
    __shared__ unsigned pos[MAXB];
    __shared__ unsigned startp[MAXB + 1];
    __shared__ unsigned gbase[MAXB];
    __shared__ uint2 srec[TILE];             // 32 KB, bucket-sorted records
    __shared__ unsigned char bmap[TILE];     // 4 KB, slot -> bucket
    const int tid = threadIdx.x;
    const int e0  = blockIdx.x * TILE;

    for (int b = tid; b < MAXB; b += SBLK) { cnt[b] = 0; pos[b] = 0; }
    __syncthreads();

    // pass 1: histogram of KEPT records + fused filtered degree (all edges)
    #pragma unroll
    for (int k = 0; k < 2; ++k) {
        int base = e0 + (k * SBLK + tid) * 4;
        if (base + 3 < n_edges) {
            int4   rv = *(const int4*)(recv + base);
            float4 lv = *(const float4*)(len + base);
            int rr[4] = {rv.x, rv.y, rv.z, rv.w};
            float ll[4] = {lv.x, lv.y, lv.z, lv.w};
            #pragma unroll
            for (int j = 0; j < 4; ++j) {
                unsigned r = (unsigned)rr[j];
                if (ll[j] < 10.0f) atomicAdd(&cnt[r >> B2SHIFT], 1u);
                if ((isCN[r >> 5] >> (r & 31)) & 1u) atomicAdd(&cn[r], 1);
            }
        } else {
            int lim = n_edges - base; if (lim < 0) lim = 0; if (lim > 4) lim = 4;
            for (int j = 0; j < lim; ++j) {
                unsigned r = (unsigned)recv[base + j];
                if (len[base + j] < 10.0f) atomicAdd(&cnt[r >> B2SHIFT], 1u);
                if ((isCN[r >> 5] >> (r & 31)) & 1u) atomicAdd(&cn[r], 1);
            }
        }
    }
    __syncthreads();

    if (tid == 0) {                           // 98-entry serial scan: trivial
        unsigned acc = 0;
        for (int b = 0; b < NB2; ++b) { startp[b] = acc; acc += cnt[b]; }
        startp[NB2] = acc;
    }
    __syncthreads();
    if (tid < NB2) gbase[tid] = atomicAdd(&cursor[tid], cnt[tid]);
    __syncthreads();

    // pass 2: reload tile (L1/L2-warm), place kept records sorted-by-bucket in LDS
    #pragma unroll
    for (int k = 0; k < 2; ++k) {
        int base = e0 + (k * SBLK + tid) * 4;
        if (base + 3 < n_edges) {
            int4   sv = *(const int4*)(send + base);
            int4   rv = *(const int4*)(recv + base);
            uint4  lv = *(const uint4*)(len + base);
            int ss[4] = {sv.x, sv.y, sv.z, sv.w};
            int rr[4] = {rv.x, rv.y, rv.z, rv.w};
            unsigned ll[4] = {lv.x, lv.y, lv.z, lv.w};
            #pragma unroll
            for (int j = 0; j < 4; ++j) {
                if (__uint_as_float(ll[j]) >= 10.0f) continue;
                unsigned r = (unsigned)rr[j];
                unsigned b = r >> B2SHIFT;
                unsigned slot = startp[b] + atomicAdd(&pos[b], 1u);
                srec[slot] = make_uint2((unsigned)ss[j] | ((r & (B2SIZE - 1)) << 17), ll[j]);
                bmap[slot] = (unsigned char)b;
            }
        } else {
            int lim = n_edges - base; if (lim < 0) lim = 0; if (lim > 4) lim = 4;
            for (int j = 0; j < lim; ++j) {
                unsigned lbits = ((const unsigned*)len)[base + j];
                if (__uint_as_float(lbits) >= 10.0f) continue;
                unsigned r = (unsigned)recv[base + j];
                unsigned b = r >> B2SHIFT;
                unsigned slot = startp[b] + atomicAdd(&pos[b], 1u);
                srec[slot] = make_uint2((unsigned)send[base + j] | ((r & (B2SIZE - 1)) << 17),
                                        lbits);
                bmap[slot] = (unsigned char)b;
            }
        }
    }
    __syncthreads();

    // phase C: coalesced copy — consecutive slots hit contiguous bucket runs
    unsigned total = startp[NB2];
    for (unsigned i = tid; i < total; i += SBLK) {
        unsigned b = bmap[i];
        unsigned g = gbase[b] + (i - startp[b]);
        uint2 rec = srec[i];
        if (g < (unsigned)cap) {
            buckets[(size_t)b * cap + g] = rec;
        } else {
            unsigned o = atomicAdd(ocur, 1u);
            unsigned r = ((unsigned)b << B2SHIFT) | ((rec.x >> 17) & (B2SIZE - 1));
            if (o < ocap) ovrec[o] = make_uint4(r, rec.x & 0x1FFFFu, rec.y, 0u);
        }
    }
}

__global__ void gnb_params(const int* __restrict__ Z, const int* __restrict__ cn,
                           float2* __restrict__ P2, int n_nodes) {
    int i = blockIdx.x * blockDim.x + threadIdx.x;
    if (i >= n_nodes) return;
    int z = Z[i];
    float Rp, C6;
    if (z == 6) {
        if (cn[i] <= 3) { Rp = 2.2348f; C6 = 429.69f; }
        else            { Rp = 1.8219f; C6 = 184.28f; }
    } else if (z == 7) {
        if (cn[i] <= 2) { Rp = 2.6454f; C6 = 720.18f; }
        else            { Rp = 2.4667f; C6 = 482.54f; }
    } else {
        float2 rc = GNB_RC6[z];
        Rp = rc.x; C6 = rc.y;
    }
    P2[i] = make_float2(sqrtf(C6), sqrtf(sqrtf(Rp)));
}

__device__ __forceinline__ float gnb_energy_eval(float2 ps, float2 pr, float rlen) {
    float env;
    if (rlen < 8.0f) {
        env = 1.0f;
    } else {
        float x = (rlen - 8.0f) * 0.5f;          // records guarantee x < 1
        float x2 = x * x;
        float x6 = x2 * x2 * x2;
        env = 1.0f - 28.0f * x6 + 48.0f * x6 * x - 21.0f * x6 * x2;
    }
    float sR  = ps.y * pr.y;                     // sqrt(R_ij)
    float C6  = ps.x * pr.x;                     // sqrt(C6_s*C6_r)
    float Rij = sR * sR;
    float R3  = Rij * Rij * Rij;
    float R6  = R3 * R3;
    float r0  = 0.4f * sR + 4.0f;
    float t   = r0 / rlen;
    float t2 = t * t, t4 = t2 * t2, t8 = t4 * t4;
    float t14 = t8 * t4 * t2;
    float fd = 1.0f / (1.0f + 6.0f * t14);
    float rl2 = rlen * rlen;
    float r6 = rl2 * rl2 * rl2;
    return -0.5f * C6 / (R6 + r6) * fd * env;
}

// Per (bin,slice): bin's P2 staged in LDS; one P2[s] gather per record.
// acc has 2 wave-pair replicas (bank-offset) to halve hot-node serialization.
__global__ void __launch_bounds__(256)
gnb_energy(const uint2* __restrict__ buckets, const unsigned* __restrict__ cursor,
           const float2* __restrict__ P2, float* __restrict__ rep,
           int cap, int n_nodes) {
    __shared__ float  acc[2][B2SIZE + 8];
    __shared__ float2 p2loc[B2SIZE];
    const int b   = blockIdx.x / ESLICES;
    const int sl  = blockIdx.x % ESLICES;
    const int tid = threadIdx.x;
    const int rr  = (tid >> 6) & 1;

    for (int i = tid; i < 2 * (B2SIZE + 8); i += 256) acc[0][i] = 0.0f;
    for (int i = tid; i < B2SIZE; i += 256) {
        int node = (b << B2SHIFT) + i;
        p2loc[i] = (node < n_nodes) ? P2[node] : make_float2(0.f, 0.f);
    }
    __syncthreads();

    unsigned count = cursor[b];
    if (count > (unsigned)cap) count = (unsigned)cap;
    unsigned seg = (count + ESLICES - 1) / ESLICES;
    unsigned st  = (unsigned)sl * seg;
    unsigned en  = st + seg; if (en > count) en = count;

    const uint2* src = buckets + (size_t)b * cap;
    for (unsigned i = st + tid; i < en; i += 256) {
        uint2 rec = src[i];
        unsigned s    = rec.x & 0x1FFFFu;
        unsigned rlow = (rec.x >> 17) & (B2SIZE - 1);
        float e = gnb_energy_eval(P2[s], p2loc[rlow], __uint_as_float(rec.y));
        atomicAdd(&acc[rr][rlow], e);
    }
    __syncthreads();

    float* dst = rep + (size_t)blockIdx.x * B2SIZE;
    for (int i = tid; i < B2SIZE; i += 256) dst[i] = acc[0][i] + acc[1][i];
}

__global__ void gnb_ovf_energy(const uint4* __restrict__ ovrec, const unsigned* __restrict__ ocur,
                               const float2* __restrict__ P2, float* __restrict__ ovf,
                               unsigned ocap) {
    unsigned n = *ocur; if (n > ocap) n = ocap;
    int stride = gridDim.x * blockDim.x;
    for (unsigned i = blockIdx.x * blockDim.x + threadIdx.x; i < n; i += stride) {
        uint4 rec = ovrec[i];
        float rlen = __uint_as_float(rec.z);
        if (rlen >= 10.0f) continue;
        float e = gnb_energy_eval(P2[rec.y], P2[rec.x], rlen);
        atomicAdd(&ovf[rec.x], e);
    }
}

__global__ void gnb_reduce(const float* __restrict__ rep, const float* __restrict__ ovf,
                           float* __restrict__ out, int n_nodes) {
    int i = blockIdx.x * blockDim.x + threadIdx.x;
    if (i >= n_nodes) return;
    int b = i >> B2SHIFT;
    int j = i & (B2SIZE - 1);
    const float* src = rep + ((size_t)b * ESLICES) * B2SIZE + j;
    float sum = ovf[i];
    #pragma unroll
    for (int s = 0; s < ESLICES; ++s) sum += src[(size_t)s * B2SIZE];
    out[i] = sum;
}

extern "C" void kernel_launch(void* const* d_in, const int* in_sizes, int n_in,
                              void* d_out, int out_size, void* d_ws, size_t ws_size,
                              hipStream_t stream) {
    const int*   Z    = (const int*)d_in[0];
    const int*   eidx = (const int*)d_in[1];
    const float* len  = (const float*)d_in[2];
    float*       out  = (float*)d_out;

    const int n_nodes = in_sizes[0];
    const int n_edges = in_sizes[2];
    const int* send = eidx;
    const int* recv = eidx + n_edges;

    const int NB2 = (n_nodes + B2SIZE - 1) >> B2SHIFT;   // 98 for n=100000
    const int nw  = (n_nodes + 31) >> 5;                 // isCN words
    const int nwp = (nw + 7) & ~7;

    // ws layout (words)
    char* ws = (char*)d_ws;
    unsigned* cursor = (unsigned*)ws;                                        // 128
    unsigned* ocur   = (unsigned*)(ws + MAXB * 4);                           // 8
    int*      cn     = (int*)(ws + (MAXB + 8) * 4);                          // n
    float*    ovf    = (float*)(ws + ((size_t)n_nodes + MAXB + 8) * 4);      // n
    float2*   P2     = (float2*)(ws + ((size_t)2 * n_nodes + MAXB + 8) * 4); // 2n
    unsigned* isCN   = (unsigned*)(ws + ((size_t)4 * n_nodes + MAXB + 8) * 4); // nwp
    float*    rep    = (float*)((char*)isCN + (size_t)nwp * 4);
    size_t rep_w     = (size_t)NB2 * ESLICES * B2SIZE;
    char*     tail   = (char*)rep + rep_w * 4;

    size_t fixed_words = (size_t)4 * n_nodes + MAXB + 8 + nwp + rep_w;
    size_t total_words = ws_size / 4;
    size_t avail = total_words > fixed_words ? total_words - fixed_words : 0;
    size_t ovw = avail / 32;                      // ~3% to overflow queue
    unsigned ocap = (unsigned)(ovw / 4);
    long cap = (long)((avail - ovw) / (2 * (size_t)NB2));
    if (cap > n_edges) cap = n_edges;
    if (cap < 0) cap = 0;
    uint4* ovrec   = (uint4*)tail;
    uint2* buckets = (uint2*)(tail + (size_t)ocap * 16);

    const int B = 256;
    int node_blocks = (n_nodes + B - 1) / B;
    int scat_blocks = (n_edges + TILE - 1) / TILE;
    int zero_words  = 2 * n_nodes + MAXB + 8;     // cursor + ocur + cn + ovf

    gnb_init<<<256, B, 0, stream>>>(Z, isCN, nw, n_nodes, (int*)ws, zero_words);
    gnb_scatter<<<scat_blocks, SBLK, 0, stream>>>(send, recv, len, isCN, cn, buckets,
                                                  cursor, ovrec, ocur, n_edges,
                                                  (int)cap, ocap, NB2);
    gnb_params<<<node_blocks, B, 0, stream>>>(Z, cn, P2, n_nodes);
    gnb_energy<<<NB2 * ESLICES, B, 0, stream>>>(buckets, cursor, P2, rep, (int)cap, n_nodes);
    gnb_ovf_energy<<<8, B, 0, stream>>>(ovrec, ocur, P2, ovf, ocap);
    gnb_reduce<<<node_blocks, B, 0, stream>>>(rep, ovf, out, n_nodes);
}